// Round 7
// baseline (476.104 us; speedup 1.0000x reference)
//
#include <hip/hip_runtime.h>
#include <stdint.h>

#define DIM 384
#define INNER 1536
#define H2X 3072
#define NE 5
#define NB 4
#define NT 1024
#define NN (NB*NT)
#define KSZ 31
#define SQZ 48
#define NASSIGN (NN*2)

typedef float floatx4 __attribute__((ext_vector_type(4)));
typedef __bf16 bf16x8 __attribute__((ext_vector_type(8)));

__device__ __forceinline__ unsigned short f2bs(float f){
  union { float f; uint32_t u; } v; v.f = f;
  uint32_t r = (v.u + 0x7fffu + ((v.u >> 16) & 1u)) >> 16;
  return (unsigned short)r;
}
__device__ __forceinline__ float bs2f(unsigned short s){
  union { uint32_t u; float f; } v; v.u = ((uint32_t)s) << 16; return v.f;
}
__device__ __forceinline__ float fsigmoid(float x){ return 1.f/(1.f+__expf(-x)); }

__device__ __forceinline__ uint32_t pk2_lo(float a, float b, uint32_t old){
  return __builtin_amdgcn_cvt_pk_fp8_f32(a, b, old, false);
}
__device__ __forceinline__ uint32_t pk2_hi(float a, float b, uint32_t old){
  return __builtin_amdgcn_cvt_pk_fp8_f32(a, b, old, true);
}
__device__ __forceinline__ uint8_t f2fp8(float a){
  return (uint8_t)__builtin_amdgcn_cvt_pk_fp8_f32(a, 0.f, 0u, false);
}

__device__ __forceinline__ void gload16(const void* g, void* l){
  __builtin_amdgcn_global_load_lds(
    reinterpret_cast<const __attribute__((address_space(1))) unsigned int*>(
        reinterpret_cast<uintptr_t>(g)),
    reinterpret_cast<__attribute__((address_space(3))) unsigned int*>(
        (unsigned int)reinterpret_cast<uintptr_t>(l)),
    16, 0, 0);
}

__device__ __forceinline__ int prefix_cnt(const int* __restrict__ cnt, int e){
  int base = 0;
  #pragma unroll
  for(int k=0;k<NE;k++) base += (k<e) ? cnt[k] : 0;
  return base;
}

#define WSCALE 8.f

// ---------------- weight transposes (one dispatch) ----------------
__device__ __forceinline__ void do_tr_bf16(const float* __restrict__ in,
    unsigned short* __restrict__ out, int R, int C, int cx, int cy){
  __shared__ float tile[32][65];
  int c0 = cx*32, r0 = cy*64;
  int tx = threadIdx.x, ty = threadIdx.y;
  #pragma unroll
  for (int i=0;i<8;i++){
    int r = ty + i*8;
    tile[tx][r] = in[(size_t)(r0+r)*C + c0 + tx];
  }
  __syncthreads();
  #pragma unroll
  for (int i=0;i<4;i++){
    int c = ty + i*8;
    uint32_t lo = f2bs(tile[c][2*tx]);
    uint32_t hi = f2bs(tile[c][2*tx+1]);
    *(uint32_t*)&out[(size_t)(c0+c)*R + r0 + 2*tx] = lo | (hi<<16);
  }
}
__device__ __forceinline__ void do_tr_fp8(const float* __restrict__ in,
    uint8_t* __restrict__ out, int R, int C, int cx, int cy){
  __shared__ float tile[32][65];
  int c0 = cx*32, r0 = cy*64;
  int tx = threadIdx.x, ty = threadIdx.y;
  #pragma unroll
  for (int i=0;i<8;i++){
    int r = ty + i*8;
    tile[tx][r] = in[(size_t)(r0+r)*C + c0 + tx];
  }
  __syncthreads();
  #pragma unroll
  for (int i=0;i<4;i++){
    int c = ty + i*8;
    uint32_t v = pk2_lo(tile[c][2*tx]*WSCALE, tile[c][2*tx+1]*WSCALE, 0u);
    *(unsigned short*)&out[(size_t)(c0+c)*R + r0 + 2*tx] = (unsigned short)(v & 0xffffu);
  }
}

#define TR_N1 (96*6*5)
#define TR_N2 (96*24*5)
#define TR_N3 (12*24*5)
#define TR_N4 (12*6)
__global__ __launch_bounds__(256) void tr_all_kernel(
    const float* __restrict__ we1, uint8_t* __restrict__ w1t,
    const float* __restrict__ we2, uint8_t* __restrict__ w2t,
    const float* __restrict__ we3, uint8_t* __restrict__ w3t,
    const float* __restrict__ rw1, unsigned short* __restrict__ rw1t){
  int bid = blockIdx.x;
  if (bid < TR_N1){
    int z = bid/(96*6), rem = bid%(96*6);
    do_tr_fp8(we1 + (size_t)z*384*3072, w1t + (size_t)z*384*3072, 384, 3072, rem%96, rem/96);
  } else if (bid < TR_N1+TR_N2){
    int idx = bid - TR_N1;
    int z = idx/(96*24), rem = idx%(96*24);
    do_tr_fp8(we2 + (size_t)z*1536*3072, w2t + (size_t)z*1536*3072, 1536, 3072, rem%96, rem/96);
  } else if (bid < TR_N1+TR_N2+TR_N3){
    int idx = bid - TR_N1 - TR_N2;
    int z = idx/(12*24), rem = idx%(12*24);
    do_tr_fp8(we3 + (size_t)z*1536*384, w3t + (size_t)z*1536*384, 1536, 384, rem%12, rem/12);
  } else {
    int idx = bid - TR_N1 - TR_N2 - TR_N3;
    do_tr_bf16(rw1, rw1t, 384, 384, idx%12, idx/12);
  }
}

// ---------------- fused LayerNorm + depthwise conv ----------------
// Sliding-window conv: 46-row register window (46 LDS reads/thread vs 496).
#define CTT 16
__global__ __launch_bounds__(384) void convln_kernel(const float* __restrict__ res,
    const float* __restrict__ ln_g, const float* __restrict__ ln_b,
    const float* __restrict__ cw, const float* __restrict__ cb,
    float* __restrict__ x, unsigned short* __restrict__ tokb, float* __restrict__ y){
  __shared__ float tile[(CTT+30)*DIM];
  int b = blockIdx.y, t0 = blockIdx.x*CTT;
  int tid = threadIdx.x;
  int w = tid>>6, lane = tid&63;
  float gw[6], bw[6];
  #pragma unroll
  for(int i=0;i<6;i++){ gw[i]=ln_g[i*64+lane]; bw[i]=ln_b[i*64+lane]; }
  for(int r=w; r<CTT+30; r+=6){
    int gt = t0 - 15 + r;
    if(gt>=0 && gt<NT){
      const float* rp = res + ((size_t)b*NT+gt)*DIM;
      float v[6]; float s=0.f;
      #pragma unroll
      for(int i=0;i<6;i++){ v[i]=rp[i*64+lane]; s+=v[i]; }
      #pragma unroll
      for(int o=32;o;o>>=1) s += __shfl_down(s,o);
      s = __shfl(s,0);
      float mean = s*(1.f/DIM);
      float q=0.f;
      #pragma unroll
      for(int i=0;i<6;i++){ v[i]-=mean; q+=v[i]*v[i]; }
      #pragma unroll
      for(int o=32;o;o>>=1) q += __shfl_down(q,o);
      q = __shfl(q,0);
      float rstd = rsqrtf(q*(1.f/DIM) + 1e-5f);
      #pragma unroll
      for(int i=0;i<6;i++) tile[r*DIM+i*64+lane] = v[i]*rstd*gw[i]+bw[i];
    } else {
      #pragma unroll
      for(int i=0;i<6;i++) tile[r*DIM+i*64+lane] = 0.f;
    }
  }
  __syncthreads();
  float cwr[KSZ];
  #pragma unroll
  for(int k=0;k<KSZ;k++) cwr[k] = cw[tid*KSZ+k];
  float bias = cb[tid];
  float win[CTT+30];
  #pragma unroll
  for(int r=0;r<CTT+30;r++) win[r] = tile[r*DIM+tid];
  #pragma unroll
  for(int t=0;t<CTT;t++){
    float acc = bias;
    #pragma unroll
    for(int k=0;k<KSZ;k++) acc += win[t+k]*cwr[k];
    size_t o = ((size_t)b*NT + t0 + t)*DIM + tid;
    y[o]=acc; tokb[o]=f2bs(acc);
    x[o]=win[t+15];
  }
}

// ---------------- router GEMM1 (bf16; also zeroes cnt/cnt2) ----------------
__global__ __launch_bounds__(256) void router_g1_kernel(const unsigned short* __restrict__ tokb,
    const unsigned short* __restrict__ rw1t, const float* __restrict__ rb1,
    unsigned short* __restrict__ g1, int* __restrict__ cnt){
  int tid = threadIdx.x;
  if(blockIdx.x==0 && blockIdx.y==0 && tid<32) cnt[tid]=0;
  __shared__ alignas(16) unsigned short sA0[128*32];
  __shared__ alignas(16) unsigned short sA1[128*32];
  __shared__ alignas(16) unsigned short sB0[128*32];
  __shared__ alignas(16) unsigned short sB1[128*32];
  int n0 = blockIdx.x*128, m0 = blockIdx.y*128;
  int lane = tid&63, wid = tid>>6, wm = wid&1, wn = wid>>1;
  int l15 = lane&15, quad = lane>>4;
  floatx4 acc[4][4];
  #pragma unroll
  for(int i=0;i<4;i++)
    #pragma unroll
    for(int j=0;j<4;j++) acc[i][j]=(floatx4){0.f,0.f,0.f,0.f};
  int rA = tid>>2, c8 = tid&3;
  const unsigned short* a0p = tokb + (size_t)(m0+rA)*DIM;
  const unsigned short* a1p = tokb + (size_t)(m0+64+rA)*DIM;
  const unsigned short* b0p = rw1t + (size_t)(n0+rA)*DIM;
  const unsigned short* b1p = rw1t + (size_t)(n0+64+rA)*DIM;

  auto stage = [&](int kt, unsigned short* dA, unsigned short* dB){
    gload16(a0p + kt + c8*8, dA + wid*512);
    gload16(a1p + kt + c8*8, dA + 2048 + wid*512);
    gload16(b0p + kt + c8*8, dB + wid*512);
    gload16(b1p + kt + c8*8, dB + 2048 + wid*512);
  };
  auto compute = [&](const unsigned short* cA, const unsigned short* cB){
    bf16x8 af[4], bfr[4];
    #pragma unroll
    for(int mi=0;mi<4;mi++) af[mi] = *(const bf16x8*)&cA[(wm*64+mi*16+l15)*32 + quad*8];
    #pragma unroll
    for(int ni=0;ni<4;ni++) bfr[ni] = *(const bf16x8*)&cB[(wn*64+ni*16+l15)*32 + quad*8];
    #pragma unroll
    for(int mi=0;mi<4;mi++)
      #pragma unroll
      for(int ni=0;ni<4;ni++)
        acc[mi][ni] = __builtin_amdgcn_mfma_f32_16x16x32_bf16(af[mi], bfr[ni], acc[mi][ni],0,0,0);
  };

  stage(0, sA0, sB0);
  __syncthreads();
  for(int kt=0; kt<DIM; kt+=64){
    if (kt+32 < DIM) stage(kt+32, sA1, sB1);
    compute(sA0, sB0);
    __syncthreads();
    if (kt+64 < DIM) stage(kt+64, sA0, sB0);
    compute(sA1, sB1);
    __syncthreads();
  }
  #pragma unroll
  for(int ni=0;ni<4;ni++){
    int col = n0 + wn*64 + ni*16 + l15;
    float bias = rb1[col];
    #pragma unroll
    for(int mi=0;mi<4;mi++){
      int rowb = m0 + wm*64 + mi*16 + quad*4;
      #pragma unroll
      for(int r=0;r<4;r++){
        float v = acc[mi][ni][r] + bias;
        g1[(size_t)(rowb+r)*DIM + col] = f2bs(v*fsigmoid(v));
      }
    }
  }
}

// ---------------- router2 ----------------
// Block covers 32 tokens; LDS histogram; one global atomic per expert per
// block (640 total vs 8192 same-line contended atomics = ~97 us idle).
__global__ __launch_bounds__(256) void router2_kernel(const unsigned short* __restrict__ g1,
    const float* __restrict__ rw2, const float* __restrict__ rb2,
    int* __restrict__ ridx, float* __restrict__ rwt, int* __restrict__ cnt){
  __shared__ int hist[8];
  int tid = threadIdx.x;
  int wid = tid>>6, lane = tid&63;
  if(tid<8) hist[tid]=0;
  __syncthreads();
  for(int it=0; it<8; ++it){
    int n = blockIdx.x*32 + wid*8 + it;
    float s[NE]={0.f,0.f,0.f,0.f,0.f};
    #pragma unroll
    for(int i=0;i<6;i++){
      int d = lane + i*64;
      float gv = bs2f(g1[(size_t)n*DIM+d]);
      #pragma unroll
      for(int e=0;e<NE;e++) s[e] += gv * rw2[d*NE+e];
    }
    #pragma unroll
    for(int e=0;e<NE;e++)
      #pragma unroll
      for(int o=32;o;o>>=1) s[e] += __shfl_down(s[e],o);
    if(lane==0){
      float r[NE];
      #pragma unroll
      for(int e=0;e<NE;e++) r[e]=s[e]+rb2[e];
      int e0=0;
      for(int e=1;e<NE;e++) if(r[e]>r[e0]) e0=e;
      int e1=-1;
      for(int e=0;e<NE;e++){ if(e==e0) continue; if(e1<0||r[e]>r[e1]) e1=e; }
      float w0 = 1.f/(1.f+__expf(r[e1]-r[e0]));
      ridx[2*n]=e0; ridx[2*n+1]=e1;
      rwt[2*n]=w0; rwt[2*n+1]=1.f-w0;
      atomicAdd(&hist[e0],1); atomicAdd(&hist[e1],1);
    }
  }
  __syncthreads();
  if(tid<NE) atomicAdd(&cnt[tid], hist[tid]);
}

// ---------------- fill positions + compact tokens to fp8 (x8) + zero pooled ----------------
// Wave-aggregated position assignment: ballot + one returning atomic per
// expert per wave; lane pos = base + wave base + rank below.
__global__ __launch_bounds__(256) void fillcompact_kernel(const int* __restrict__ ridx,
    const int* __restrict__ cnt, int* __restrict__ cnt2,
    int* __restrict__ inv, const unsigned short* __restrict__ tokb,
    uint8_t* __restrict__ tokc, float* __restrict__ pooled){
  __shared__ int sSrc[256], sPos[256];
  int tid = threadIdx.x;
  if(blockIdx.x==0){
    for(int i=tid;i<NB*DIM;i+=256) pooled[i]=0.f;
  }
  int i = blockIdx.x*256 + tid;
  int e = ridx[i];
  int base = prefix_cnt(cnt, e);
  int lane = tid&63;
  unsigned long long below = (1ull<<lane)-1ull;
  int pos = 0;
  #pragma unroll
  for(int ex=0; ex<NE; ex++){
    unsigned long long m = __ballot(e==ex);
    if(m){
      int ldr = __ffsll((long long)m)-1;
      int nb = 0;
      if(lane==ldr) nb = atomicAdd(&cnt2[ex], (int)__popcll(m));
      nb = __shfl(nb, ldr);
      if(e==ex) pos = base + nb + (int)__popcll(m & below);
    }
  }
  inv[i] = pos;
  sSrc[tid] = i>>1;
  sPos[tid] = pos;
  __syncthreads();
  int w = tid>>6;
  for(int j=0;j<64;j++){
    int idx = w*64+j;
    int src = sSrc[idx], dst = sPos[idx];
    if(lane<48){
      uint4 sv = ((const uint4*)&tokb[(size_t)src*DIM])[lane];
      float f0=bs2f(sv.x&0xffff)*WSCALE, f1=bs2f(sv.x>>16)*WSCALE;
      float f2=bs2f(sv.y&0xffff)*WSCALE, f3=bs2f(sv.y>>16)*WSCALE;
      float f4=bs2f(sv.z&0xffff)*WSCALE, f5=bs2f(sv.z>>16)*WSCALE;
      float f6=bs2f(sv.w&0xffff)*WSCALE, f7=bs2f(sv.w>>16)*WSCALE;
      uint32_t lo = pk2_hi(f2,f3, pk2_lo(f0,f1,0u));
      uint32_t hi = pk2_hi(f6,f7, pk2_lo(f4,f5,0u));
      uint2 pv; pv.x = lo; pv.y = hi;
      ((uint2*)&tokc[(size_t)dst*DIM])[lane] = pv;
    }
  }
}

// ---------------- fp8 expert GEMM + fused SwiGLU ----------------
// R4-proven structure (measured best: A+B via LDS, b64 fragment reads; the
// ~9.6M bank-conflict cycles are measured-harmless — R5's conflict-free
// variant was SLOWER). One change vs R4: j-tile grouping x2 — each block
// computes two adjacent 128-col tiles sequentially, reusing acc regs after
// the first epilogue. Blocks 1596->798 (< 1024 resident slots -> single
// occupancy round) and prologue/epilogue amortized 2x.
template<int KDIM>
__device__ __forceinline__ void gemm_swiglu_impl(
    const uint8_t* __restrict__ A,
    const uint8_t* __restrict__ wt, const float* __restrict__ bias,
    const int* __restrict__ cnt, uint8_t* __restrict__ out,
    float inv_scale, float out_scale){
  int e = blockIdx.z;
  int cn = cnt[e];
  int mtile = blockIdx.y;
  if (mtile*64 >= cn) return;
  int base = prefix_cnt(cnt, e);
  int tid=threadIdx.x, lane=tid&63, wid=tid>>6;
  int l15=lane&15, quad=lane>>4;
  __shared__ alignas(16) uint8_t sA0[64*64];
  __shared__ alignas(16) uint8_t sA1[64*64];
  __shared__ alignas(16) uint8_t sBa0[128*64];
  __shared__ alignas(16) uint8_t sBa1[128*64];
  __shared__ alignas(16) uint8_t sBg0[128*64];
  __shared__ alignas(16) uint8_t sBg1[128*64];
  int rA = tid>>2;
  int gb = ((tid&3) ^ ((tid>>3)&3))*16;   // swizzled global chunk offset
  const uint8_t* a0p = A + (size_t)(base + min(mtile*64+rA, cn-1))*KDIM + gb;
  int ldsw = wid*1024;

  for(int g=0; g<2; ++g){
    int j0 = blockIdx.x*256 + g*128;
    const uint8_t* b0p = wt + ((size_t)e*H2X + j0 + rA)*KDIM + gb;
    const uint8_t* b1p = wt + ((size_t)e*H2X + j0 + 64 + rA)*KDIM + gb;
    const uint8_t* g0p = wt + ((size_t)e*H2X + INNER + j0 + rA)*KDIM + gb;
    const uint8_t* g1p = wt + ((size_t)e*H2X + INNER + j0 + 64 + rA)*KDIM + gb;
    floatx4 aca[4][2], acg[4][2];
    #pragma unroll
    for(int i=0;i<4;i++)
      #pragma unroll
      for(int j=0;j<2;j++){ aca[i][j]=(floatx4){0.f,0.f,0.f,0.f}; acg[i][j]=(floatx4){0.f,0.f,0.f,0.f}; }

    auto stage = [&](int kt, uint8_t* dA, uint8_t* dBa, uint8_t* dBg){
      gload16(a0p + kt, dA + ldsw);
      gload16(b0p + kt, dBa + ldsw);
      gload16(b1p + kt, dBa + 4096 + ldsw);
      gload16(g0p + kt, dBg + ldsw);
      gload16(g1p + kt, dBg + 4096 + ldsw);
    };
    auto compute = [&](const uint8_t* cA, const uint8_t* cBa, const uint8_t* cBg){
      #pragma unroll
      for(int s=0;s<2;s++){
        int pq = (((s*4+quad) ^ (l15&6)))*8;
        long af[4], ba[2], bg[2];
        #pragma unroll
        for(int mi=0;mi<4;mi++) af[mi] = *(const long*)&cA[(mi*16+l15)*64 + pq];
        #pragma unroll
        for(int ni=0;ni<2;ni++){
          int col = wid*32 + ni*16 + l15;
          ba[ni] = *(const long*)&cBa[col*64 + pq];
          bg[ni] = *(const long*)&cBg[col*64 + pq];
        }
        #pragma unroll
        for(int mi=0;mi<4;mi++)
          #pragma unroll
          for(int ni=0;ni<2;ni++){
            aca[mi][ni] = __builtin_amdgcn_mfma_f32_16x16x32_fp8_fp8(af[mi], ba[ni], aca[mi][ni],0,0,0);
            acg[mi][ni] = __builtin_amdgcn_mfma_f32_16x16x32_fp8_fp8(af[mi], bg[ni], acg[mi][ni],0,0,0);
          }
      }
    };

    stage(0, sA0, sBa0, sBg0);
    __syncthreads();
    for(int kt=0; kt<KDIM; kt+=128){
      if (kt+64 < KDIM) stage(kt+64, sA1, sBa1, sBg1);
      compute(sA0, sBa0, sBg0);
      __syncthreads();
      if (kt+128 < KDIM) stage(kt+128, sA0, sBa0, sBg0);
      compute(sA1, sBa1, sBg1);
      __syncthreads();
    }

    #pragma unroll
    for(int ni=0;ni<2;ni++){
      int j = j0 + wid*32 + ni*16 + l15;
      float ba_ = bias[e*H2X + j];
      float bg_ = bias[e*H2X + INNER + j];
      #pragma unroll
      for(int mi=0;mi<4;mi++){
        int rl = mi*16 + quad*4;
        #pragma unroll
        for(int r=0;r<4;r++){
          int row = mtile*64 + rl + r;
          if(row < cn){
            float a = aca[mi][ni][r]*inv_scale + ba_;
            float gg = acg[mi][ni][r]*inv_scale + bg_;
            out[(size_t)(base+row)*INNER + j] = f2fp8(a*gg*fsigmoid(gg)*out_scale);
          }
        }
      }
    }
  }
}

__global__ __launch_bounds__(256,3) void gemm_sg1_kernel(
    const uint8_t* __restrict__ A, const uint8_t* __restrict__ wt,
    const float* __restrict__ bias, const int* __restrict__ cnt, uint8_t* __restrict__ out){
  gemm_swiglu_impl<DIM>(A, wt, bias, cnt, out, 1.f/64.f, 64.f);
}
__global__ __launch_bounds__(256,3) void gemm_sg2_kernel(
    const uint8_t* __restrict__ A, const uint8_t* __restrict__ wt,
    const float* __restrict__ bias, const int* __restrict__ cnt, uint8_t* __restrict__ out){
  gemm_swiglu_impl<INNER>(A, wt, bias, cnt, out, 1.f/512.f, 2097152.f);
}

// ---------------- fp8 expert output GEMM, split-K=2 -> two eo slabs ----------------
// R4 form: M=64 tile, 4 waves in 1x4 over N=128; acc = 32 AGPR.
__global__ __launch_bounds__(256,4) void gemm_out_kernel(
    const uint8_t* __restrict__ h2, const uint8_t* __restrict__ w3t,
    const float* __restrict__ be3, const int* __restrict__ cnt, float* __restrict__ eo){
  int e = blockIdx.z;
  int cn = cnt[e];
  int mtile = blockIdx.y;
  if (mtile*64 >= cn) return;
  int base = prefix_cnt(cnt, e);
  int jt = blockIdx.x % 3, kh = blockIdx.x / 3;
  int n0 = jt*128;
  int koff = kh*768;
  float* eos = eo + (size_t)kh*NASSIGN*DIM;
  int tid=threadIdx.x, lane=tid&63, wid=tid>>6;
  int l15=lane&15, quad=lane>>4;
  __shared__ alignas(16) uint8_t sA0[64*64];
  __shared__ alignas(16) uint8_t sA1[64*64];
  __shared__ alignas(16) uint8_t sB0[128*64];
  __shared__ alignas(16) uint8_t sB1[128*64];
  int rA = tid>>2;
  int gb = ((tid&3) ^ ((tid>>3)&3))*16;
  const uint8_t* a0p = h2 + (size_t)(base + min(mtile*64+rA, cn-1))*INNER + koff + gb;
  const uint8_t* b0p = w3t + ((size_t)e*DIM + n0 + rA)*INNER + koff + gb;
  const uint8_t* b1p = w3t + ((size_t)e*DIM + n0 + 64 + rA)*INNER + koff + gb;
  floatx4 acc[4][2];
  #pragma unroll
  for(int i=0;i<4;i++)
    #pragma unroll
    for(int j=0;j<2;j++) acc[i][j]=(floatx4){0.f,0.f,0.f,0.f};
  int ldsw = wid*1024;

  auto stage = [&](int kt, uint8_t* dA, uint8_t* dB){
    gload16(a0p + kt, dA + ldsw);
    gload16(b0p + kt, dB + ldsw);
    gload16(b1p + kt, dB + 4096 + ldsw);
  };
  auto compute = [&](const uint8_t* cA, const uint8_t* cB){
    #pragma unroll
    for(int s=0;s<2;s++){
      int pq = (((s*4+quad) ^ (l15&6)))*8;
      long af[4], bfr[2];
      #pragma unroll
      for(int mi=0;mi<4;mi++) af[mi] = *(const long*)&cA[(mi*16+l15)*64 + pq];
      #pragma unroll
      for(int ni=0;ni<2;ni++){
        int col = wid*32 + ni*16 + l15;
        bfr[ni] = *(const long*)&cB[col*64 + pq];
      }
      #pragma unroll
      for(int mi=0;mi<4;mi++)
        #pragma unroll
        for(int ni=0;ni<2;ni++)
          acc[mi][ni] = __builtin_amdgcn_mfma_f32_16x16x32_fp8_fp8(af[mi], bfr[ni], acc[mi][ni],0,0,0);
    }
  };

  stage(0, sA0, sB0);
  __syncthreads();
  for(int kt=0; kt<768; kt+=128){
    if (kt+64 < 768) stage(kt+64, sA1, sB1);
    compute(sA0, sB0);
    __syncthreads();
    if (kt+128 < 768) stage(kt+128, sA0, sB0);
    compute(sA1, sB1);
    __syncthreads();
  }

  const float OSC = 5.9604644775390625e-8f;  // 2^-24
  #pragma unroll
  for(int ni=0;ni<2;ni++){
    int col = n0 + wid*32 + ni*16 + l15;
    float b3 = (kh==0) ? be3[e*DIM + col] : 0.f;
    #pragma unroll
    for(int mi=0;mi<4;mi++){
      int rl = mi*16 + quad*4;
      #pragma unroll
      for(int r=0;r<4;r++){
        int row = mtile*64 + rl + r;
        if(row < cn){
          eos[(size_t)(base+row)*DIM + col] = acc[mi][ni][r]*OSC + b3;
        }
      }
    }
  }
}

// ---------------- combine expert outputs + pooled accumulation ----------------
__global__ __launch_bounds__(384) void combine_pooled_kernel(const float* __restrict__ eo,
    const int* __restrict__ inv, const float* __restrict__ rwt,
    const float* __restrict__ x, const float* __restrict__ sres,
    float* __restrict__ y, float* __restrict__ pooled){
  int b = blockIdx.y, t0 = blockIdx.x*8;
  int d = threadIdx.x;
  const float* eo1 = eo + (size_t)NASSIGN*DIM;
  float sr = sres[d];
  float acc = 0.f;
  for(int t=0;t<8;t++){
    int n = b*NT + t0 + t;
    int p0 = inv[2*n], p1 = inv[2*n+1];
    float w0 = rwt[2*n], w1 = rwt[2*n+1];
    size_t o = (size_t)n*DIM + d;
    float yv = y[o] + w0*(eo[(size_t)p0*DIM+d] + eo1[(size_t)p0*DIM+d])
                    + w1*(eo[(size_t)p1*DIM+d] + eo1[(size_t)p1*DIM+d]);
    y[o] = yv;
    acc += x[o]*sr + yv;
  }
  atomicAdd(&pooled[b*DIM+d], acc*(1.f/NT));
}

// ---------------- fused gate + final ----------------
__global__ __launch_bounds__(384) void gatefinal_kernel(const float* __restrict__ pooled,
    const float* __restrict__ sw1, const float* __restrict__ sb1,
    const float* __restrict__ sw2, const float* __restrict__ sb2,
    const float* __restrict__ res, const float* __restrict__ y, float* __restrict__ out){
  int b = blockIdx.y, t0 = blockIdx.x*8;
  int d = threadIdx.x;
  __shared__ float sp[DIM];
  __shared__ float sh[SQZ];
  sp[d] = pooled[b*DIM+d];
  __syncthreads();
  if(d<SQZ){
    float a = sb1[d];
    for(int k=0;k<DIM;k++) a += sp[k]*sw1[k*SQZ+d];
    sh[d] = a*fsigmoid(a);
  }
  __syncthreads();
  float a = sb2[d];
  #pragma unroll
  for(int j=0;j<SQZ;j++) a += sh[j]*sw2[j*DIM+d];
  float g = fsigmoid(a);
  for(int t=0;t<8;t++){
    size_t o = ((size_t)b*NT + t0 + t)*DIM + d;
    out[o] = res[o] + y[o]*g;
  }
}

extern "C" void kernel_launch(void* const* d_in, const int* in_sizes, int n_in,
                              void* d_out, int out_size, void* d_ws, size_t ws_size,
                              hipStream_t stream) {
  (void)in_sizes; (void)n_in; (void)out_size; (void)ws_size;
  const float* res   = (const float*)d_in[0];
  const float* ln_g  = (const float*)d_in[1];
  const float* ln_b  = (const float*)d_in[2];
  const float* conv_w= (const float*)d_in[3];
  const float* conv_b= (const float*)d_in[4];
  const float* rw1   = (const float*)d_in[5];
  const float* rb1   = (const float*)d_in[6];
  const float* rw2   = (const float*)d_in[7];
  const float* rb2   = (const float*)d_in[8];
  const float* we1   = (const float*)d_in[9];
  const float* be1   = (const float*)d_in[10];
  const float* we2   = (const float*)d_in[11];
  const float* be2   = (const float*)d_in[12];
  const float* we3   = (const float*)d_in[13];
  const float* be3   = (const float*)d_in[14];
  const float* sw1   = (const float*)d_in[15];
  const float* sb1   = (const float*)d_in[16];
  const float* sw2   = (const float*)d_in[17];
  const float* sb2   = (const float*)d_in[18];
  const float* sres  = (const float*)d_in[19];
  float* out = (float*)d_out;

  char* ws = (char*)d_ws;
  size_t off = 0;
  auto alloc = [&](size_t bytes)->void*{ void* p = ws + off; off = (off + bytes + 255) & ~(size_t)255; return p; };
  float*          x     = (float*)alloc((size_t)NN*DIM*4);
  float*          y     = (float*)alloc((size_t)NN*DIM*4);
  float*          eo    = (float*)alloc((size_t)2*NASSIGN*DIM*4);
  unsigned short* tokb  = (unsigned short*)alloc((size_t)NN*DIM*2);
  uint8_t*        tokc  = (uint8_t*)alloc((size_t)NASSIGN*DIM);
  unsigned short* g1    = (unsigned short*)alloc((size_t)NN*DIM*2);
  uint8_t*        w1t   = (uint8_t*)alloc((size_t)NE*H2X*DIM);
  uint8_t*        w2t   = (uint8_t*)alloc((size_t)NE*H2X*INNER);
  uint8_t*        w3t   = (uint8_t*)alloc((size_t)NE*DIM*INNER);
  unsigned short* rw1t  = (unsigned short*)alloc((size_t)DIM*DIM*2);
  uint8_t*        h1    = (uint8_t*)alloc((size_t)NASSIGN*INNER);
  uint8_t*        h2b   = (uint8_t*)alloc((size_t)NASSIGN*INNER);
  int*            ridx  = (int*)alloc((size_t)NASSIGN*4);
  float*          rwt   = (float*)alloc((size_t)NASSIGN*4);
  int*            inv   = (int*)alloc((size_t)NASSIGN*4);
  int*            cnt   = (int*)alloc(128);
  int*            cnt2  = cnt + 8;
  float*          pooled= (float*)alloc((size_t)NB*DIM*4);

  tr_all_kernel<<<TR_N1+TR_N2+TR_N3+TR_N4, dim3(32,8), 0, stream>>>(
      we1, w1t, we2, w2t, we3, w3t, rw1, rw1t);
  convln_kernel<<<dim3(NT/CTT, NB), 384, 0, stream>>>(
      res, ln_g, ln_b, conv_w, conv_b, x, tokb, y);
  router_g1_kernel<<<dim3(DIM/128, NN/128), 256, 0, stream>>>(tokb, rw1t, rb1, g1, cnt);
  router2_kernel<<<NN/32, 256, 0, stream>>>(g1, rw2, rb2, ridx, rwt, cnt);
  fillcompact_kernel<<<NASSIGN/256, 256, 0, stream>>>(ridx, cnt, cnt2, inv, tokb, tokc, pooled);

  gemm_sg1_kernel<<<dim3(INNER/256, NN/64, NE), 256, 0, stream>>>(tokc, w1t, be1, cnt, h1);
  gemm_sg2_kernel<<<dim3(INNER/256, NN/64, NE), 256, 0, stream>>>(h1, w2t, be2, cnt, h2b);
  gemm_out_kernel<<<dim3(6, NN/64, NE), 256, 0, stream>>>(h2b, w3t, be3, cnt, eo);
  combine_pooled_kernel<<<dim3(NT/8, NB), 384, 0, stream>>>(
      eo, inv, rwt, x, sres, y, pooled);
  gatefinal_kernel<<<dim3(NT/8, NB), 384, 0, stream>>>(
      pooled, sw1, sb1, sw2, sb2, res, y, out);
}

// Round 8
// 473.324 us; speedup vs baseline: 1.0059x; 1.0059x over previous
//
#include <hip/hip_runtime.h>
#include <stdint.h>

#define DIM 384
#define INNER 1536
#define H2X 3072
#define NE 5
#define NB 4
#define NT 1024
#define NN (NB*NT)
#define KSZ 31
#define SQZ 48
#define NASSIGN (NN*2)

typedef float floatx4 __attribute__((ext_vector_type(4)));
typedef __bf16 bf16x8 __attribute__((ext_vector_type(8)));

__device__ __forceinline__ unsigned short f2bs(float f){
  union { float f; uint32_t u; } v; v.f = f;
  uint32_t r = (v.u + 0x7fffu + ((v.u >> 16) & 1u)) >> 16;
  return (unsigned short)r;
}
__device__ __forceinline__ float bs2f(unsigned short s){
  union { uint32_t u; float f; } v; v.u = ((uint32_t)s) << 16; return v.f;
}
__device__ __forceinline__ float fsigmoid(float x){ return 1.f/(1.f+__expf(-x)); }

__device__ __forceinline__ uint32_t pk2_lo(float a, float b, uint32_t old){
  return __builtin_amdgcn_cvt_pk_fp8_f32(a, b, old, false);
}
__device__ __forceinline__ uint32_t pk2_hi(float a, float b, uint32_t old){
  return __builtin_amdgcn_cvt_pk_fp8_f32(a, b, old, true);
}
__device__ __forceinline__ uint8_t f2fp8(float a){
  return (uint8_t)__builtin_amdgcn_cvt_pk_fp8_f32(a, 0.f, 0u, false);
}

__device__ __forceinline__ void gload16(const void* g, void* l){
  __builtin_amdgcn_global_load_lds(
    reinterpret_cast<const __attribute__((address_space(1))) unsigned int*>(
        reinterpret_cast<uintptr_t>(g)),
    reinterpret_cast<__attribute__((address_space(3))) unsigned int*>(
        (unsigned int)reinterpret_cast<uintptr_t>(l)),
    16, 0, 0);
}

__device__ __forceinline__ int prefix_cnt(const int* __restrict__ cnt, int e){
  int base = 0;
  #pragma unroll
  for(int k=0;k<NE;k++) base += (k<e) ? cnt[k] : 0;
  return base;
}

#define WSCALE 8.f

// ---------------- weight transposes (one dispatch) ----------------
__device__ __forceinline__ void do_tr_bf16(const float* __restrict__ in,
    unsigned short* __restrict__ out, int R, int C, int cx, int cy){
  __shared__ float tile[32][65];
  int c0 = cx*32, r0 = cy*64;
  int tx = threadIdx.x, ty = threadIdx.y;
  #pragma unroll
  for (int i=0;i<8;i++){
    int r = ty + i*8;
    tile[tx][r] = in[(size_t)(r0+r)*C + c0 + tx];
  }
  __syncthreads();
  #pragma unroll
  for (int i=0;i<4;i++){
    int c = ty + i*8;
    uint32_t lo = f2bs(tile[c][2*tx]);
    uint32_t hi = f2bs(tile[c][2*tx+1]);
    *(uint32_t*)&out[(size_t)(c0+c)*R + r0 + 2*tx] = lo | (hi<<16);
  }
}
__device__ __forceinline__ void do_tr_fp8(const float* __restrict__ in,
    uint8_t* __restrict__ out, int R, int C, int cx, int cy){
  __shared__ float tile[32][65];
  int c0 = cx*32, r0 = cy*64;
  int tx = threadIdx.x, ty = threadIdx.y;
  #pragma unroll
  for (int i=0;i<8;i++){
    int r = ty + i*8;
    tile[tx][r] = in[(size_t)(r0+r)*C + c0 + tx];
  }
  __syncthreads();
  #pragma unroll
  for (int i=0;i<4;i++){
    int c = ty + i*8;
    uint32_t v = pk2_lo(tile[c][2*tx]*WSCALE, tile[c][2*tx+1]*WSCALE, 0u);
    *(unsigned short*)&out[(size_t)(c0+c)*R + r0 + 2*tx] = (unsigned short)(v & 0xffffu);
  }
}

#define TR_N1 (96*6*5)
#define TR_N2 (96*24*5)
#define TR_N3 (12*24*5)
#define TR_N4 (12*6)
__global__ __launch_bounds__(256) void tr_all_kernel(
    const float* __restrict__ we1, uint8_t* __restrict__ w1t,
    const float* __restrict__ we2, uint8_t* __restrict__ w2t,
    const float* __restrict__ we3, uint8_t* __restrict__ w3t,
    const float* __restrict__ rw1, unsigned short* __restrict__ rw1t){
  int bid = blockIdx.x;
  if (bid < TR_N1){
    int z = bid/(96*6), rem = bid%(96*6);
    do_tr_fp8(we1 + (size_t)z*384*3072, w1t + (size_t)z*384*3072, 384, 3072, rem%96, rem/96);
  } else if (bid < TR_N1+TR_N2){
    int idx = bid - TR_N1;
    int z = idx/(96*24), rem = idx%(96*24);
    do_tr_fp8(we2 + (size_t)z*1536*3072, w2t + (size_t)z*1536*3072, 1536, 3072, rem%96, rem/96);
  } else if (bid < TR_N1+TR_N2+TR_N3){
    int idx = bid - TR_N1 - TR_N2;
    int z = idx/(12*24), rem = idx%(12*24);
    do_tr_fp8(we3 + (size_t)z*1536*384, w3t + (size_t)z*1536*384, 1536, 384, rem%12, rem/12);
  } else {
    int idx = bid - TR_N1 - TR_N2 - TR_N3;
    do_tr_bf16(rw1, rw1t, 384, 384, idx%12, idx/12);
  }
}

// ---------------- fused LayerNorm + depthwise conv ----------------
// Sliding-window conv: 46-row register window (46 LDS reads/thread vs 496).
#define CTT 16
__global__ __launch_bounds__(384) void convln_kernel(const float* __restrict__ res,
    const float* __restrict__ ln_g, const float* __restrict__ ln_b,
    const float* __restrict__ cw, const float* __restrict__ cb,
    float* __restrict__ x, unsigned short* __restrict__ tokb, float* __restrict__ y){
  __shared__ float tile[(CTT+30)*DIM];
  int b = blockIdx.y, t0 = blockIdx.x*CTT;
  int tid = threadIdx.x;
  int w = tid>>6, lane = tid&63;
  float gw[6], bw[6];
  #pragma unroll
  for(int i=0;i<6;i++){ gw[i]=ln_g[i*64+lane]; bw[i]=ln_b[i*64+lane]; }
  for(int r=w; r<CTT+30; r+=6){
    int gt = t0 - 15 + r;
    if(gt>=0 && gt<NT){
      const float* rp = res + ((size_t)b*NT+gt)*DIM;
      float v[6]; float s=0.f;
      #pragma unroll
      for(int i=0;i<6;i++){ v[i]=rp[i*64+lane]; s+=v[i]; }
      #pragma unroll
      for(int o=32;o;o>>=1) s += __shfl_down(s,o);
      s = __shfl(s,0);
      float mean = s*(1.f/DIM);
      float q=0.f;
      #pragma unroll
      for(int i=0;i<6;i++){ v[i]-=mean; q+=v[i]*v[i]; }
      #pragma unroll
      for(int o=32;o;o>>=1) q += __shfl_down(q,o);
      q = __shfl(q,0);
      float rstd = rsqrtf(q*(1.f/DIM) + 1e-5f);
      #pragma unroll
      for(int i=0;i<6;i++) tile[r*DIM+i*64+lane] = v[i]*rstd*gw[i]+bw[i];
    } else {
      #pragma unroll
      for(int i=0;i<6;i++) tile[r*DIM+i*64+lane] = 0.f;
    }
  }
  __syncthreads();
  float cwr[KSZ];
  #pragma unroll
  for(int k=0;k<KSZ;k++) cwr[k] = cw[tid*KSZ+k];
  float bias = cb[tid];
  float win[CTT+30];
  #pragma unroll
  for(int r=0;r<CTT+30;r++) win[r] = tile[r*DIM+tid];
  #pragma unroll
  for(int t=0;t<CTT;t++){
    float acc = bias;
    #pragma unroll
    for(int k=0;k<KSZ;k++) acc += win[t+k]*cwr[k];
    size_t o = ((size_t)b*NT + t0 + t)*DIM + tid;
    y[o]=acc; tokb[o]=f2bs(acc);
    x[o]=win[t+15];
  }
}

// ---------------- router GEMM1 (bf16; also zeroes cnt/cnt2) ----------------
__global__ __launch_bounds__(256) void router_g1_kernel(const unsigned short* __restrict__ tokb,
    const unsigned short* __restrict__ rw1t, const float* __restrict__ rb1,
    unsigned short* __restrict__ g1, int* __restrict__ cnt){
  int tid = threadIdx.x;
  if(blockIdx.x==0 && blockIdx.y==0 && tid<32) cnt[tid]=0;
  __shared__ alignas(16) unsigned short sA0[128*32];
  __shared__ alignas(16) unsigned short sA1[128*32];
  __shared__ alignas(16) unsigned short sB0[128*32];
  __shared__ alignas(16) unsigned short sB1[128*32];
  int n0 = blockIdx.x*128, m0 = blockIdx.y*128;
  int lane = tid&63, wid = tid>>6, wm = wid&1, wn = wid>>1;
  int l15 = lane&15, quad = lane>>4;
  floatx4 acc[4][4];
  #pragma unroll
  for(int i=0;i<4;i++)
    #pragma unroll
    for(int j=0;j<4;j++) acc[i][j]=(floatx4){0.f,0.f,0.f,0.f};
  int rA = tid>>2, c8 = tid&3;
  const unsigned short* a0p = tokb + (size_t)(m0+rA)*DIM;
  const unsigned short* a1p = tokb + (size_t)(m0+64+rA)*DIM;
  const unsigned short* b0p = rw1t + (size_t)(n0+rA)*DIM;
  const unsigned short* b1p = rw1t + (size_t)(n0+64+rA)*DIM;

  auto stage = [&](int kt, unsigned short* dA, unsigned short* dB){
    gload16(a0p + kt + c8*8, dA + wid*512);
    gload16(a1p + kt + c8*8, dA + 2048 + wid*512);
    gload16(b0p + kt + c8*8, dB + wid*512);
    gload16(b1p + kt + c8*8, dB + 2048 + wid*512);
  };
  auto compute = [&](const unsigned short* cA, const unsigned short* cB){
    bf16x8 af[4], bfr[4];
    #pragma unroll
    for(int mi=0;mi<4;mi++) af[mi] = *(const bf16x8*)&cA[(wm*64+mi*16+l15)*32 + quad*8];
    #pragma unroll
    for(int ni=0;ni<4;ni++) bfr[ni] = *(const bf16x8*)&cB[(wn*64+ni*16+l15)*32 + quad*8];
    #pragma unroll
    for(int mi=0;mi<4;mi++)
      #pragma unroll
      for(int ni=0;ni<4;ni++)
        acc[mi][ni] = __builtin_amdgcn_mfma_f32_16x16x32_bf16(af[mi], bfr[ni], acc[mi][ni],0,0,0);
  };

  stage(0, sA0, sB0);
  __syncthreads();
  for(int kt=0; kt<DIM; kt+=64){
    if (kt+32 < DIM) stage(kt+32, sA1, sB1);
    compute(sA0, sB0);
    __syncthreads();
    if (kt+64 < DIM) stage(kt+64, sA0, sB0);
    compute(sA1, sB1);
    __syncthreads();
  }
  #pragma unroll
  for(int ni=0;ni<4;ni++){
    int col = n0 + wn*64 + ni*16 + l15;
    float bias = rb1[col];
    #pragma unroll
    for(int mi=0;mi<4;mi++){
      int rowb = m0 + wm*64 + mi*16 + quad*4;
      #pragma unroll
      for(int r=0;r<4;r++){
        float v = acc[mi][ni][r] + bias;
        g1[(size_t)(rowb+r)*DIM + col] = f2bs(v*fsigmoid(v));
      }
    }
  }
}

// ---------------- router2 ----------------
// Block covers 32 tokens; LDS histogram; one global atomic per expert per
// block (640 total vs 8192 same-line contended atomics = ~97 us idle).
__global__ __launch_bounds__(256) void router2_kernel(const unsigned short* __restrict__ g1,
    const float* __restrict__ rw2, const float* __restrict__ rb2,
    int* __restrict__ ridx, float* __restrict__ rwt, int* __restrict__ cnt){
  __shared__ int hist[8];
  int tid = threadIdx.x;
  int wid = tid>>6, lane = tid&63;
  if(tid<8) hist[tid]=0;
  __syncthreads();
  for(int it=0; it<8; ++it){
    int n = blockIdx.x*32 + wid*8 + it;
    float s[NE]={0.f,0.f,0.f,0.f,0.f};
    #pragma unroll
    for(int i=0;i<6;i++){
      int d = lane + i*64;
      float gv = bs2f(g1[(size_t)n*DIM+d]);
      #pragma unroll
      for(int e=0;e<NE;e++) s[e] += gv * rw2[d*NE+e];
    }
    #pragma unroll
    for(int e=0;e<NE;e++)
      #pragma unroll
      for(int o=32;o;o>>=1) s[e] += __shfl_down(s[e],o);
    if(lane==0){
      float r[NE];
      #pragma unroll
      for(int e=0;e<NE;e++) r[e]=s[e]+rb2[e];
      int e0=0;
      for(int e=1;e<NE;e++) if(r[e]>r[e0]) e0=e;
      int e1=-1;
      for(int e=0;e<NE;e++){ if(e==e0) continue; if(e1<0||r[e]>r[e1]) e1=e; }
      float w0 = 1.f/(1.f+__expf(r[e1]-r[e0]));
      ridx[2*n]=e0; ridx[2*n+1]=e1;
      rwt[2*n]=w0; rwt[2*n+1]=1.f-w0;
      atomicAdd(&hist[e0],1); atomicAdd(&hist[e1],1);
    }
  }
  __syncthreads();
  if(tid<NE) atomicAdd(&cnt[tid], hist[tid]);
}

// ---------------- fill positions + compact tokens to fp8 (x8) + zero pooled ----------------
// Wave-aggregated position assignment: ballot + one returning atomic per
// expert per wave; lane pos = base + wave base + rank below.
__global__ __launch_bounds__(256) void fillcompact_kernel(const int* __restrict__ ridx,
    const int* __restrict__ cnt, int* __restrict__ cnt2,
    int* __restrict__ inv, const unsigned short* __restrict__ tokb,
    uint8_t* __restrict__ tokc, float* __restrict__ pooled){
  __shared__ int sSrc[256], sPos[256];
  int tid = threadIdx.x;
  if(blockIdx.x==0){
    for(int i=tid;i<NB*DIM;i+=256) pooled[i]=0.f;
  }
  int i = blockIdx.x*256 + tid;
  int e = ridx[i];
  int base = prefix_cnt(cnt, e);
  int lane = tid&63;
  unsigned long long below = (1ull<<lane)-1ull;
  int pos = 0;
  #pragma unroll
  for(int ex=0; ex<NE; ex++){
    unsigned long long m = __ballot(e==ex);
    if(m){
      int ldr = __ffsll((long long)m)-1;
      int nb = 0;
      if(lane==ldr) nb = atomicAdd(&cnt2[ex], (int)__popcll(m));
      nb = __shfl(nb, ldr);
      if(e==ex) pos = base + nb + (int)__popcll(m & below);
    }
  }
  inv[i] = pos;
  sSrc[tid] = i>>1;
  sPos[tid] = pos;
  __syncthreads();
  int w = tid>>6;
  for(int j=0;j<64;j++){
    int idx = w*64+j;
    int src = sSrc[idx], dst = sPos[idx];
    if(lane<48){
      uint4 sv = ((const uint4*)&tokb[(size_t)src*DIM])[lane];
      float f0=bs2f(sv.x&0xffff)*WSCALE, f1=bs2f(sv.x>>16)*WSCALE;
      float f2=bs2f(sv.y&0xffff)*WSCALE, f3=bs2f(sv.y>>16)*WSCALE;
      float f4=bs2f(sv.z&0xffff)*WSCALE, f5=bs2f(sv.z>>16)*WSCALE;
      float f6=bs2f(sv.w&0xffff)*WSCALE, f7=bs2f(sv.w>>16)*WSCALE;
      uint32_t lo = pk2_hi(f2,f3, pk2_lo(f0,f1,0u));
      uint32_t hi = pk2_hi(f6,f7, pk2_lo(f4,f5,0u));
      uint2 pv; pv.x = lo; pv.y = hi;
      ((uint2*)&tokc[(size_t)dst*DIM])[lane] = pv;
    }
  }
}

// ---------------- fp8 expert GEMM + fused SwiGLU ----------------
// Exact R4 inner structure (measured best). One change: M-GROUPING x2 —
// each block processes two 64-row m-tiles sequentially at a fixed j0.
// B pointers are g-invariant (hoisted; no R7-style address bloat); A is
// staged once per m-tile (no extra A traffic — R7's j-grouping doubled
// A fetches, FETCH 79->140MB). Active blocks ~1560 -> ~780 < 1024
// resident slots -> single occupancy round, tail eliminated.
template<int KDIM>
__device__ __forceinline__ void gemm_swiglu_impl(
    const uint8_t* __restrict__ A,
    const uint8_t* __restrict__ wt, const float* __restrict__ bias,
    const int* __restrict__ cnt, uint8_t* __restrict__ out,
    float inv_scale, float out_scale){
  int e = blockIdx.z;
  int cn = cnt[e];
  int mtile = blockIdx.y;
  if (mtile*128 >= cn) return;
  int base = prefix_cnt(cnt, e);
  int j0 = blockIdx.x*128;
  int tid=threadIdx.x, lane=tid&63, wid=tid>>6;
  int l15=lane&15, quad=lane>>4;
  __shared__ alignas(16) uint8_t sA0[64*64];
  __shared__ alignas(16) uint8_t sA1[64*64];
  __shared__ alignas(16) uint8_t sBa0[128*64];
  __shared__ alignas(16) uint8_t sBa1[128*64];
  __shared__ alignas(16) uint8_t sBg0[128*64];
  __shared__ alignas(16) uint8_t sBg1[128*64];
  int rA = tid>>2;
  int gb = ((tid&3) ^ ((tid>>3)&3))*16;   // swizzled global chunk offset
  const uint8_t* b0p = wt + ((size_t)e*H2X + j0 + rA)*KDIM + gb;
  const uint8_t* b1p = wt + ((size_t)e*H2X + j0 + 64 + rA)*KDIM + gb;
  const uint8_t* g0p = wt + ((size_t)e*H2X + INNER + j0 + rA)*KDIM + gb;
  const uint8_t* g1p = wt + ((size_t)e*H2X + INNER + j0 + 64 + rA)*KDIM + gb;
  int ldsw = wid*1024;

  #pragma unroll 1
  for(int g=0; g<2; ++g){
    int m0 = mtile*128 + g*64;
    if (m0 >= cn) break;
    const uint8_t* a0p = A + (size_t)(base + min(m0+rA, cn-1))*KDIM + gb;
    floatx4 aca[4][2], acg[4][2];
    #pragma unroll
    for(int i=0;i<4;i++)
      #pragma unroll
      for(int j=0;j<2;j++){ aca[i][j]=(floatx4){0.f,0.f,0.f,0.f}; acg[i][j]=(floatx4){0.f,0.f,0.f,0.f}; }

    auto stage = [&](int kt, uint8_t* dA, uint8_t* dBa, uint8_t* dBg){
      gload16(a0p + kt, dA + ldsw);
      gload16(b0p + kt, dBa + ldsw);
      gload16(b1p + kt, dBa + 4096 + ldsw);
      gload16(g0p + kt, dBg + ldsw);
      gload16(g1p + kt, dBg + 4096 + ldsw);
    };
    auto compute = [&](const uint8_t* cA, const uint8_t* cBa, const uint8_t* cBg){
      #pragma unroll
      for(int s=0;s<2;s++){
        int pq = (((s*4+quad) ^ (l15&6)))*8;
        long af[4], ba[2], bg[2];
        #pragma unroll
        for(int mi=0;mi<4;mi++) af[mi] = *(const long*)&cA[(mi*16+l15)*64 + pq];
        #pragma unroll
        for(int ni=0;ni<2;ni++){
          int col = wid*32 + ni*16 + l15;
          ba[ni] = *(const long*)&cBa[col*64 + pq];
          bg[ni] = *(const long*)&cBg[col*64 + pq];
        }
        #pragma unroll
        for(int mi=0;mi<4;mi++)
          #pragma unroll
          for(int ni=0;ni<2;ni++){
            aca[mi][ni] = __builtin_amdgcn_mfma_f32_16x16x32_fp8_fp8(af[mi], ba[ni], aca[mi][ni],0,0,0);
            acg[mi][ni] = __builtin_amdgcn_mfma_f32_16x16x32_fp8_fp8(af[mi], bg[ni], acg[mi][ni],0,0,0);
          }
      }
    };

    stage(0, sA0, sBa0, sBg0);
    __syncthreads();
    for(int kt=0; kt<KDIM; kt+=128){
      if (kt+64 < KDIM) stage(kt+64, sA1, sBa1, sBg1);
      compute(sA0, sBa0, sBg0);
      __syncthreads();
      if (kt+128 < KDIM) stage(kt+128, sA0, sBa0, sBg0);
      compute(sA1, sBa1, sBg1);
      __syncthreads();
    }

    #pragma unroll
    for(int ni=0;ni<2;ni++){
      int j = j0 + wid*32 + ni*16 + l15;
      float ba_ = bias[e*H2X + j];
      float bg_ = bias[e*H2X + INNER + j];
      #pragma unroll
      for(int mi=0;mi<4;mi++){
        int rl = mi*16 + quad*4;
        #pragma unroll
        for(int r=0;r<4;r++){
          int row = m0 + rl + r;
          if(row < cn){
            float a = aca[mi][ni][r]*inv_scale + ba_;
            float gg = acg[mi][ni][r]*inv_scale + bg_;
            out[(size_t)(base+row)*INNER + j] = f2fp8(a*gg*fsigmoid(gg)*out_scale);
          }
        }
      }
    }
  }
}

__global__ __launch_bounds__(256,3) void gemm_sg1_kernel(
    const uint8_t* __restrict__ A, const uint8_t* __restrict__ wt,
    const float* __restrict__ bias, const int* __restrict__ cnt, uint8_t* __restrict__ out){
  gemm_swiglu_impl<DIM>(A, wt, bias, cnt, out, 1.f/64.f, 64.f);
}
__global__ __launch_bounds__(256,3) void gemm_sg2_kernel(
    const uint8_t* __restrict__ A, const uint8_t* __restrict__ wt,
    const float* __restrict__ bias, const int* __restrict__ cnt, uint8_t* __restrict__ out){
  gemm_swiglu_impl<INNER>(A, wt, bias, cnt, out, 1.f/512.f, 2097152.f);
}

// ---------------- fp8 expert output GEMM, split-K=2 -> two eo slabs ----------------
// R4 form: M=64 tile, 4 waves in 1x4 over N=128; acc = 32 AGPR.
__global__ __launch_bounds__(256,4) void gemm_out_kernel(
    const uint8_t* __restrict__ h2, const uint8_t* __restrict__ w3t,
    const float* __restrict__ be3, const int* __restrict__ cnt, float* __restrict__ eo){
  int e = blockIdx.z;
  int cn = cnt[e];
  int mtile = blockIdx.y;
  if (mtile*64 >= cn) return;
  int base = prefix_cnt(cnt, e);
  int jt = blockIdx.x % 3, kh = blockIdx.x / 3;
  int n0 = jt*128;
  int koff = kh*768;
  float* eos = eo + (size_t)kh*NASSIGN*DIM;
  int tid=threadIdx.x, lane=tid&63, wid=tid>>6;
  int l15=lane&15, quad=lane>>4;
  __shared__ alignas(16) uint8_t sA0[64*64];
  __shared__ alignas(16) uint8_t sA1[64*64];
  __shared__ alignas(16) uint8_t sB0[128*64];
  __shared__ alignas(16) uint8_t sB1[128*64];
  int rA = tid>>2;
  int gb = ((tid&3) ^ ((tid>>3)&3))*16;
  const uint8_t* a0p = h2 + (size_t)(base + min(mtile*64+rA, cn-1))*INNER + koff + gb;
  const uint8_t* b0p = w3t + ((size_t)e*DIM + n0 + rA)*INNER + koff + gb;
  const uint8_t* b1p = w3t + ((size_t)e*DIM + n0 + 64 + rA)*INNER + koff + gb;
  floatx4 acc[4][2];
  #pragma unroll
  for(int i=0;i<4;i++)
    #pragma unroll
    for(int j=0;j<2;j++) acc[i][j]=(floatx4){0.f,0.f,0.f,0.f};
  int ldsw = wid*1024;

  auto stage = [&](int kt, uint8_t* dA, uint8_t* dB){
    gload16(a0p + kt, dA + ldsw);
    gload16(b0p + kt, dB + ldsw);
    gload16(b1p + kt, dB + 4096 + ldsw);
  };
  auto compute = [&](const uint8_t* cA, const uint8_t* cB){
    #pragma unroll
    for(int s=0;s<2;s++){
      int pq = (((s*4+quad) ^ (l15&6)))*8;
      long af[4], bfr[2];
      #pragma unroll
      for(int mi=0;mi<4;mi++) af[mi] = *(const long*)&cA[(mi*16+l15)*64 + pq];
      #pragma unroll
      for(int ni=0;ni<2;ni++){
        int col = wid*32 + ni*16 + l15;
        bfr[ni] = *(const long*)&cB[col*64 + pq];
      }
      #pragma unroll
      for(int mi=0;mi<4;mi++)
        #pragma unroll
        for(int ni=0;ni<2;ni++)
          acc[mi][ni] = __builtin_amdgcn_mfma_f32_16x16x32_fp8_fp8(af[mi], bfr[ni], acc[mi][ni],0,0,0);
    }
  };

  stage(0, sA0, sB0);
  __syncthreads();
  for(int kt=0; kt<768; kt+=128){
    if (kt+64 < 768) stage(kt+64, sA1, sB1);
    compute(sA0, sB0);
    __syncthreads();
    if (kt+128 < 768) stage(kt+128, sA0, sB0);
    compute(sA1, sB1);
    __syncthreads();
  }

  const float OSC = 5.9604644775390625e-8f;  // 2^-24
  #pragma unroll
  for(int ni=0;ni<2;ni++){
    int col = n0 + wid*32 + ni*16 + l15;
    float b3 = (kh==0) ? be3[e*DIM + col] : 0.f;
    #pragma unroll
    for(int mi=0;mi<4;mi++){
      int rl = mi*16 + quad*4;
      #pragma unroll
      for(int r=0;r<4;r++){
        int row = mtile*64 + rl + r;
        if(row < cn){
          eos[(size_t)(base+row)*DIM + col] = acc[mi][ni][r]*OSC + b3;
        }
      }
    }
  }
}

// ---------------- combine expert outputs + pooled accumulation ----------------
__global__ __launch_bounds__(384) void combine_pooled_kernel(const float* __restrict__ eo,
    const int* __restrict__ inv, const float* __restrict__ rwt,
    const float* __restrict__ x, const float* __restrict__ sres,
    float* __restrict__ y, float* __restrict__ pooled){
  int b = blockIdx.y, t0 = blockIdx.x*8;
  int d = threadIdx.x;
  const float* eo1 = eo + (size_t)NASSIGN*DIM;
  float sr = sres[d];
  float acc = 0.f;
  for(int t=0;t<8;t++){
    int n = b*NT + t0 + t;
    int p0 = inv[2*n], p1 = inv[2*n+1];
    float w0 = rwt[2*n], w1 = rwt[2*n+1];
    size_t o = (size_t)n*DIM + d;
    float yv = y[o] + w0*(eo[(size_t)p0*DIM+d] + eo1[(size_t)p0*DIM+d])
                    + w1*(eo[(size_t)p1*DIM+d] + eo1[(size_t)p1*DIM+d]);
    y[o] = yv;
    acc += x[o]*sr + yv;
  }
  atomicAdd(&pooled[b*DIM+d], acc*(1.f/NT));
}

// ---------------- fused gate + final ----------------
__global__ __launch_bounds__(384) void gatefinal_kernel(const float* __restrict__ pooled,
    const float* __restrict__ sw1, const float* __restrict__ sb1,
    const float* __restrict__ sw2, const float* __restrict__ sb2,
    const float* __restrict__ res, const float* __restrict__ y, float* __restrict__ out){
  int b = blockIdx.y, t0 = blockIdx.x*8;
  int d = threadIdx.x;
  __shared__ float sp[DIM];
  __shared__ float sh[SQZ];
  sp[d] = pooled[b*DIM+d];
  __syncthreads();
  if(d<SQZ){
    float a = sb1[d];
    for(int k=0;k<DIM;k++) a += sp[k]*sw1[k*SQZ+d];
    sh[d] = a*fsigmoid(a);
  }
  __syncthreads();
  float a = sb2[d];
  #pragma unroll
  for(int j=0;j<SQZ;j++) a += sh[j]*sw2[j*DIM+d];
  float g = fsigmoid(a);
  for(int t=0;t<8;t++){
    size_t o = ((size_t)b*NT + t0 + t)*DIM + d;
    out[o] = res[o] + y[o]*g;
  }
}

extern "C" void kernel_launch(void* const* d_in, const int* in_sizes, int n_in,
                              void* d_out, int out_size, void* d_ws, size_t ws_size,
                              hipStream_t stream) {
  (void)in_sizes; (void)n_in; (void)out_size; (void)ws_size;
  const float* res   = (const float*)d_in[0];
  const float* ln_g  = (const float*)d_in[1];
  const float* ln_b  = (const float*)d_in[2];
  const float* conv_w= (const float*)d_in[3];
  const float* conv_b= (const float*)d_in[4];
  const float* rw1   = (const float*)d_in[5];
  const float* rb1   = (const float*)d_in[6];
  const float* rw2   = (const float*)d_in[7];
  const float* rb2   = (const float*)d_in[8];
  const float* we1   = (const float*)d_in[9];
  const float* be1   = (const float*)d_in[10];
  const float* we2   = (const float*)d_in[11];
  const float* be2   = (const float*)d_in[12];
  const float* we3   = (const float*)d_in[13];
  const float* be3   = (const float*)d_in[14];
  const float* sw1   = (const float*)d_in[15];
  const float* sb1   = (const float*)d_in[16];
  const float* sw2   = (const float*)d_in[17];
  const float* sb2   = (const float*)d_in[18];
  const float* sres  = (const float*)d_in[19];
  float* out = (float*)d_out;

  char* ws = (char*)d_ws;
  size_t off = 0;
  auto alloc = [&](size_t bytes)->void*{ void* p = ws + off; off = (off + bytes + 255) & ~(size_t)255; return p; };
  float*          x     = (float*)alloc((size_t)NN*DIM*4);
  float*          y     = (float*)alloc((size_t)NN*DIM*4);
  float*          eo    = (float*)alloc((size_t)2*NASSIGN*DIM*4);
  unsigned short* tokb  = (unsigned short*)alloc((size_t)NN*DIM*2);
  uint8_t*        tokc  = (uint8_t*)alloc((size_t)NASSIGN*DIM);
  unsigned short* g1    = (unsigned short*)alloc((size_t)NN*DIM*2);
  uint8_t*        w1t   = (uint8_t*)alloc((size_t)NE*H2X*DIM);
  uint8_t*        w2t   = (uint8_t*)alloc((size_t)NE*H2X*INNER);
  uint8_t*        w3t   = (uint8_t*)alloc((size_t)NE*DIM*INNER);
  unsigned short* rw1t  = (unsigned short*)alloc((size_t)DIM*DIM*2);
  uint8_t*        h1    = (uint8_t*)alloc((size_t)NASSIGN*INNER);
  uint8_t*        h2b   = (uint8_t*)alloc((size_t)NASSIGN*INNER);
  int*            ridx  = (int*)alloc((size_t)NASSIGN*4);
  float*          rwt   = (float*)alloc((size_t)NASSIGN*4);
  int*            inv   = (int*)alloc((size_t)NASSIGN*4);
  int*            cnt   = (int*)alloc(128);
  int*            cnt2  = cnt + 8;
  float*          pooled= (float*)alloc((size_t)NB*DIM*4);

  tr_all_kernel<<<TR_N1+TR_N2+TR_N3+TR_N4, dim3(32,8), 0, stream>>>(
      we1, w1t, we2, w2t, we3, w3t, rw1, rw1t);
  convln_kernel<<<dim3(NT/CTT, NB), 384, 0, stream>>>(
      res, ln_g, ln_b, conv_w, conv_b, x, tokb, y);
  router_g1_kernel<<<dim3(DIM/128, NN/128), 256, 0, stream>>>(tokb, rw1t, rb1, g1, cnt);
  router2_kernel<<<NN/32, 256, 0, stream>>>(g1, rw2, rb2, ridx, rwt, cnt);
  fillcompact_kernel<<<NASSIGN/256, 256, 0, stream>>>(ridx, cnt, cnt2, inv, tokb, tokc, pooled);

  gemm_sg1_kernel<<<dim3(INNER/128, NN/128, NE), 256, 0, stream>>>(tokc, w1t, be1, cnt, h1);
  gemm_sg2_kernel<<<dim3(INNER/128, NN/128, NE), 256, 0, stream>>>(h1, w2t, be2, cnt, h2b);
  gemm_out_kernel<<<dim3(6, NN/64, NE), 256, 0, stream>>>(h2b, w3t, be3, cnt, eo);
  combine_pooled_kernel<<<dim3(NT/8, NB), 384, 0, stream>>>(
      eo, inv, rwt, x, sres, y, pooled);
  gatefinal_kernel<<<dim3(NT/8, NB), 384, 0, stream>>>(
      pooled, sw1, sb1, sw2, sb2, res, y, out);
}

// Round 9
// 455.226 us; speedup vs baseline: 1.0459x; 1.0398x over previous
//
#include <hip/hip_runtime.h>
#include <stdint.h>

#define DIM 384
#define INNER 1536
#define H2X 3072
#define NE 5
#define NB 4
#define NT 1024
#define NN (NB*NT)
#define KSZ 31
#define SQZ 48
#define NASSIGN (NN*2)

typedef float floatx4 __attribute__((ext_vector_type(4)));
typedef __bf16 bf16x8 __attribute__((ext_vector_type(8)));

__device__ __forceinline__ unsigned short f2bs(float f){
  union { float f; uint32_t u; } v; v.f = f;
  uint32_t r = (v.u + 0x7fffu + ((v.u >> 16) & 1u)) >> 16;
  return (unsigned short)r;
}
__device__ __forceinline__ float bs2f(unsigned short s){
  union { uint32_t u; float f; } v; v.u = ((uint32_t)s) << 16; return v.f;
}
__device__ __forceinline__ float fsigmoid(float x){ return 1.f/(1.f+__expf(-x)); }

__device__ __forceinline__ uint32_t pk2_lo(float a, float b, uint32_t old){
  return __builtin_amdgcn_cvt_pk_fp8_f32(a, b, old, false);
}
__device__ __forceinline__ uint32_t pk2_hi(float a, float b, uint32_t old){
  return __builtin_amdgcn_cvt_pk_fp8_f32(a, b, old, true);
}
__device__ __forceinline__ uint8_t f2fp8(float a){
  return (uint8_t)__builtin_amdgcn_cvt_pk_fp8_f32(a, 0.f, 0u, false);
}

__device__ __forceinline__ void gload16(const void* g, void* l){
  __builtin_amdgcn_global_load_lds(
    reinterpret_cast<const __attribute__((address_space(1))) unsigned int*>(
        reinterpret_cast<uintptr_t>(g)),
    reinterpret_cast<__attribute__((address_space(3))) unsigned int*>(
        (unsigned int)reinterpret_cast<uintptr_t>(l)),
    16, 0, 0);
}

__device__ __forceinline__ int prefix_cnt(const int* __restrict__ cnt, int e){
  int base = 0;
  #pragma unroll
  for(int k=0;k<NE;k++) base += (k<e) ? cnt[k] : 0;
  return base;
}

#define WSCALE 8.f

// ---------------- weight transposes (one dispatch) ----------------
__device__ __forceinline__ void do_tr_bf16(const float* __restrict__ in,
    unsigned short* __restrict__ out, int R, int C, int cx, int cy){
  __shared__ float tile[32][65];
  int c0 = cx*32, r0 = cy*64;
  int tx = threadIdx.x, ty = threadIdx.y;
  #pragma unroll
  for (int i=0;i<8;i++){
    int r = ty + i*8;
    tile[tx][r] = in[(size_t)(r0+r)*C + c0 + tx];
  }
  __syncthreads();
  #pragma unroll
  for (int i=0;i<4;i++){
    int c = ty + i*8;
    uint32_t lo = f2bs(tile[c][2*tx]);
    uint32_t hi = f2bs(tile[c][2*tx+1]);
    *(uint32_t*)&out[(size_t)(c0+c)*R + r0 + 2*tx] = lo | (hi<<16);
  }
}
__device__ __forceinline__ void do_tr_fp8(const float* __restrict__ in,
    uint8_t* __restrict__ out, int R, int C, int cx, int cy){
  __shared__ float tile[32][65];
  int c0 = cx*32, r0 = cy*64;
  int tx = threadIdx.x, ty = threadIdx.y;
  #pragma unroll
  for (int i=0;i<8;i++){
    int r = ty + i*8;
    tile[tx][r] = in[(size_t)(r0+r)*C + c0 + tx];
  }
  __syncthreads();
  #pragma unroll
  for (int i=0;i<4;i++){
    int c = ty + i*8;
    uint32_t v = pk2_lo(tile[c][2*tx]*WSCALE, tile[c][2*tx+1]*WSCALE, 0u);
    *(unsigned short*)&out[(size_t)(c0+c)*R + r0 + 2*tx] = (unsigned short)(v & 0xffffu);
  }
}

#define TR_N1 (96*6*5)
#define TR_N2 (96*24*5)
#define TR_N3 (12*24*5)
#define TR_N4 (12*6)
__global__ __launch_bounds__(256) void tr_all_kernel(
    const float* __restrict__ we1, uint8_t* __restrict__ w1t,
    const float* __restrict__ we2, uint8_t* __restrict__ w2t,
    const float* __restrict__ we3, uint8_t* __restrict__ w3t,
    const float* __restrict__ rw1, unsigned short* __restrict__ rw1t){
  int bid = blockIdx.x;
  if (bid < TR_N1){
    int z = bid/(96*6), rem = bid%(96*6);
    do_tr_fp8(we1 + (size_t)z*384*3072, w1t + (size_t)z*384*3072, 384, 3072, rem%96, rem/96);
  } else if (bid < TR_N1+TR_N2){
    int idx = bid - TR_N1;
    int z = idx/(96*24), rem = idx%(96*24);
    do_tr_fp8(we2 + (size_t)z*1536*3072, w2t + (size_t)z*1536*3072, 1536, 3072, rem%96, rem/96);
  } else if (bid < TR_N1+TR_N2+TR_N3){
    int idx = bid - TR_N1 - TR_N2;
    int z = idx/(12*24), rem = idx%(12*24);
    do_tr_fp8(we3 + (size_t)z*1536*384, w3t + (size_t)z*1536*384, 1536, 384, rem%12, rem/12);
  } else {
    int idx = bid - TR_N1 - TR_N2 - TR_N3;
    do_tr_bf16(rw1, rw1t, 384, 384, idx%12, idx/12);
  }
}

// ---------------- fused LayerNorm + depthwise conv ----------------
// Sliding-window conv: 46-row register window (46 LDS reads/thread vs 496).
#define CTT 16
__global__ __launch_bounds__(384) void convln_kernel(const float* __restrict__ res,
    const float* __restrict__ ln_g, const float* __restrict__ ln_b,
    const float* __restrict__ cw, const float* __restrict__ cb,
    float* __restrict__ x, unsigned short* __restrict__ tokb, float* __restrict__ y){
  __shared__ float tile[(CTT+30)*DIM];
  int b = blockIdx.y, t0 = blockIdx.x*CTT;
  int tid = threadIdx.x;
  int w = tid>>6, lane = tid&63;
  float gw[6], bw[6];
  #pragma unroll
  for(int i=0;i<6;i++){ gw[i]=ln_g[i*64+lane]; bw[i]=ln_b[i*64+lane]; }
  for(int r=w; r<CTT+30; r+=6){
    int gt = t0 - 15 + r;
    if(gt>=0 && gt<NT){
      const float* rp = res + ((size_t)b*NT+gt)*DIM;
      float v[6]; float s=0.f;
      #pragma unroll
      for(int i=0;i<6;i++){ v[i]=rp[i*64+lane]; s+=v[i]; }
      #pragma unroll
      for(int o=32;o;o>>=1) s += __shfl_down(s,o);
      s = __shfl(s,0);
      float mean = s*(1.f/DIM);
      float q=0.f;
      #pragma unroll
      for(int i=0;i<6;i++){ v[i]-=mean; q+=v[i]*v[i]; }
      #pragma unroll
      for(int o=32;o;o>>=1) q += __shfl_down(q,o);
      q = __shfl(q,0);
      float rstd = rsqrtf(q*(1.f/DIM) + 1e-5f);
      #pragma unroll
      for(int i=0;i<6;i++) tile[r*DIM+i*64+lane] = v[i]*rstd*gw[i]+bw[i];
    } else {
      #pragma unroll
      for(int i=0;i<6;i++) tile[r*DIM+i*64+lane] = 0.f;
    }
  }
  __syncthreads();
  float cwr[KSZ];
  #pragma unroll
  for(int k=0;k<KSZ;k++) cwr[k] = cw[tid*KSZ+k];
  float bias = cb[tid];
  float win[CTT+30];
  #pragma unroll
  for(int r=0;r<CTT+30;r++) win[r] = tile[r*DIM+tid];
  #pragma unroll
  for(int t=0;t<CTT;t++){
    float acc = bias;
    #pragma unroll
    for(int k=0;k<KSZ;k++) acc += win[t+k]*cwr[k];
    size_t o = ((size_t)b*NT + t0 + t)*DIM + tid;
    y[o]=acc; tokb[o]=f2bs(acc);
    x[o]=win[t+15];
  }
}

// ---------------- router GEMM1 (bf16; also zeroes cnt/cnt2) ----------------
__global__ __launch_bounds__(256) void router_g1_kernel(const unsigned short* __restrict__ tokb,
    const unsigned short* __restrict__ rw1t, const float* __restrict__ rb1,
    unsigned short* __restrict__ g1, int* __restrict__ cnt){
  int tid = threadIdx.x;
  if(blockIdx.x==0 && blockIdx.y==0 && tid<32) cnt[tid]=0;
  __shared__ alignas(16) unsigned short sA0[128*32];
  __shared__ alignas(16) unsigned short sA1[128*32];
  __shared__ alignas(16) unsigned short sB0[128*32];
  __shared__ alignas(16) unsigned short sB1[128*32];
  int n0 = blockIdx.x*128, m0 = blockIdx.y*128;
  int lane = tid&63, wid = tid>>6, wm = wid&1, wn = wid>>1;
  int l15 = lane&15, quad = lane>>4;
  floatx4 acc[4][4];
  #pragma unroll
  for(int i=0;i<4;i++)
    #pragma unroll
    for(int j=0;j<4;j++) acc[i][j]=(floatx4){0.f,0.f,0.f,0.f};
  int rA = tid>>2, c8 = tid&3;
  const unsigned short* a0p = tokb + (size_t)(m0+rA)*DIM;
  const unsigned short* a1p = tokb + (size_t)(m0+64+rA)*DIM;
  const unsigned short* b0p = rw1t + (size_t)(n0+rA)*DIM;
  const unsigned short* b1p = rw1t + (size_t)(n0+64+rA)*DIM;

  auto stage = [&](int kt, unsigned short* dA, unsigned short* dB){
    gload16(a0p + kt + c8*8, dA + wid*512);
    gload16(a1p + kt + c8*8, dA + 2048 + wid*512);
    gload16(b0p + kt + c8*8, dB + wid*512);
    gload16(b1p + kt + c8*8, dB + 2048 + wid*512);
  };
  auto compute = [&](const unsigned short* cA, const unsigned short* cB){
    bf16x8 af[4], bfr[4];
    #pragma unroll
    for(int mi=0;mi<4;mi++) af[mi] = *(const bf16x8*)&cA[(wm*64+mi*16+l15)*32 + quad*8];
    #pragma unroll
    for(int ni=0;ni<4;ni++) bfr[ni] = *(const bf16x8*)&cB[(wn*64+ni*16+l15)*32 + quad*8];
    #pragma unroll
    for(int mi=0;mi<4;mi++)
      #pragma unroll
      for(int ni=0;ni<4;ni++)
        acc[mi][ni] = __builtin_amdgcn_mfma_f32_16x16x32_bf16(af[mi], bfr[ni], acc[mi][ni],0,0,0);
  };

  stage(0, sA0, sB0);
  __syncthreads();
  for(int kt=0; kt<DIM; kt+=64){
    if (kt+32 < DIM) stage(kt+32, sA1, sB1);
    compute(sA0, sB0);
    __syncthreads();
    if (kt+64 < DIM) stage(kt+64, sA0, sB0);
    compute(sA1, sB1);
    __syncthreads();
  }
  #pragma unroll
  for(int ni=0;ni<4;ni++){
    int col = n0 + wn*64 + ni*16 + l15;
    float bias = rb1[col];
    #pragma unroll
    for(int mi=0;mi<4;mi++){
      int rowb = m0 + wm*64 + mi*16 + quad*4;
      #pragma unroll
      for(int r=0;r<4;r++){
        float v = acc[mi][ni][r] + bias;
        g1[(size_t)(rowb+r)*DIM + col] = f2bs(v*fsigmoid(v));
      }
    }
  }
}

// ---------------- router2 ----------------
// Block covers 32 tokens; LDS histogram; one global atomic per expert per
// block (640 total vs 8192 same-line contended atomics = ~97 us idle).
__global__ __launch_bounds__(256) void router2_kernel(const unsigned short* __restrict__ g1,
    const float* __restrict__ rw2, const float* __restrict__ rb2,
    int* __restrict__ ridx, float* __restrict__ rwt, int* __restrict__ cnt){
  __shared__ int hist[8];
  int tid = threadIdx.x;
  int wid = tid>>6, lane = tid&63;
  if(tid<8) hist[tid]=0;
  __syncthreads();
  for(int it=0; it<8; ++it){
    int n = blockIdx.x*32 + wid*8 + it;
    float s[NE]={0.f,0.f,0.f,0.f,0.f};
    #pragma unroll
    for(int i=0;i<6;i++){
      int d = lane + i*64;
      float gv = bs2f(g1[(size_t)n*DIM+d]);
      #pragma unroll
      for(int e=0;e<NE;e++) s[e] += gv * rw2[d*NE+e];
    }
    #pragma unroll
    for(int e=0;e<NE;e++)
      #pragma unroll
      for(int o=32;o;o>>=1) s[e] += __shfl_down(s[e],o);
    if(lane==0){
      float r[NE];
      #pragma unroll
      for(int e=0;e<NE;e++) r[e]=s[e]+rb2[e];
      int e0=0;
      for(int e=1;e<NE;e++) if(r[e]>r[e0]) e0=e;
      int e1=-1;
      for(int e=0;e<NE;e++){ if(e==e0) continue; if(e1<0||r[e]>r[e1]) e1=e; }
      float w0 = 1.f/(1.f+__expf(r[e1]-r[e0]));
      ridx[2*n]=e0; ridx[2*n+1]=e1;
      rwt[2*n]=w0; rwt[2*n+1]=1.f-w0;
      atomicAdd(&hist[e0],1); atomicAdd(&hist[e1],1);
    }
  }
  __syncthreads();
  if(tid<NE) atomicAdd(&cnt[tid], hist[tid]);
}

// ---------------- fill positions + compact tokens to fp8 (x8) + zero pooled ----------------
// Re-gridded 32->256 blocks: 32 assignments/block (wave-0 ballot; lanes>=32
// carry e=-1 and never match), copy loop is 8 rows/wave instead of 64 and
// runs on all 256 CUs instead of 32.
__global__ __launch_bounds__(256) void fillcompact_kernel(const int* __restrict__ ridx,
    const int* __restrict__ cnt, int* __restrict__ cnt2,
    int* __restrict__ inv, const unsigned short* __restrict__ tokb,
    uint8_t* __restrict__ tokc, float* __restrict__ pooled){
  __shared__ int sSrc[32], sPos[32];
  int tid = threadIdx.x;
  if(blockIdx.x==0){
    for(int i=tid;i<NB*DIM;i+=256) pooled[i]=0.f;
  }
  int lane = tid&63;
  if(tid<64){
    int i = blockIdx.x*32 + lane;
    int e = (lane<32) ? ridx[i] : -1;
    int base = (lane<32) ? prefix_cnt(cnt, e) : 0;
    unsigned long long below = (1ull<<lane)-1ull;
    int pos = 0;
    #pragma unroll
    for(int ex=0; ex<NE; ex++){
      unsigned long long m = __ballot(e==ex);
      if(m){
        int ldr = __ffsll((long long)m)-1;
        int nb = 0;
        if(lane==ldr) nb = atomicAdd(&cnt2[ex], (int)__popcll(m));
        nb = __shfl(nb, ldr);
        if(e==ex) pos = base + nb + (int)__popcll(m & below);
      }
    }
    if(lane<32){
      inv[i] = pos;
      sSrc[lane] = i>>1;
      sPos[lane] = pos;
    }
  }
  __syncthreads();
  int w = tid>>6;
  for(int j=0;j<8;j++){
    int idx = w*8+j;
    int src = sSrc[idx], dst = sPos[idx];
    if(lane<48){
      uint4 sv = ((const uint4*)&tokb[(size_t)src*DIM])[lane];
      float f0=bs2f(sv.x&0xffff)*WSCALE, f1=bs2f(sv.x>>16)*WSCALE;
      float f2=bs2f(sv.y&0xffff)*WSCALE, f3=bs2f(sv.y>>16)*WSCALE;
      float f4=bs2f(sv.z&0xffff)*WSCALE, f5=bs2f(sv.z>>16)*WSCALE;
      float f6=bs2f(sv.w&0xffff)*WSCALE, f7=bs2f(sv.w>>16)*WSCALE;
      uint32_t lo = pk2_hi(f2,f3, pk2_lo(f0,f1,0u));
      uint32_t hi = pk2_hi(f6,f7, pk2_lo(f4,f5,0u));
      uint2 pv; pv.x = lo; pv.y = hi;
      ((uint2*)&tokc[(size_t)dst*DIM])[lane] = pv;
    }
  }
}

// ---------------- fp8 expert GEMM + fused SwiGLU ----------------
// EXACT R4 inner structure (measured best: 90us sg2; R5/R6/R7/R8 variants
// all regressed — any grouping loop costs ~12 VGPR, crosses the 128-total-reg
// boundary, drops 4->3 waves/SIMD). Grid is flattened 1D, PANEL-MAJOR:
// id = (e*12 + x)*64 + y, so all 64 m-tiles sharing one (expert,j0) B-panel
// are temporally contiguous -> each XCD's L2 holds 1-2 panels (~0.8MB)
// instead of all 12 (4.7MB > 4MB L2 thrash; R4 measured 79MB HBM fetch vs
// 36MB ideal, ~1.5GB of L3 B-panel traffic during sg2).
template<int KDIM>
__device__ __forceinline__ void gemm_swiglu_impl(
    const uint8_t* __restrict__ A,
    const uint8_t* __restrict__ wt, const float* __restrict__ bias,
    const int* __restrict__ cnt, uint8_t* __restrict__ out,
    float inv_scale, float out_scale, int xtile, int mtile, int e){
  int cn = cnt[e];
  if (mtile*64 >= cn) return;
  int base = prefix_cnt(cnt, e);
  int j0 = xtile*128;
  int tid=threadIdx.x, lane=tid&63, wid=tid>>6;
  int l15=lane&15, quad=lane>>4;
  __shared__ alignas(16) uint8_t sA0[64*64];
  __shared__ alignas(16) uint8_t sA1[64*64];
  __shared__ alignas(16) uint8_t sBa0[128*64];
  __shared__ alignas(16) uint8_t sBa1[128*64];
  __shared__ alignas(16) uint8_t sBg0[128*64];
  __shared__ alignas(16) uint8_t sBg1[128*64];
  int rA = tid>>2;
  int gb = ((tid&3) ^ ((tid>>3)&3))*16;   // swizzled global chunk offset
  const uint8_t* a0p = A + (size_t)(base + min(mtile*64+rA, cn-1))*KDIM + gb;
  const uint8_t* b0p = wt + ((size_t)e*H2X + j0 + rA)*KDIM + gb;
  const uint8_t* b1p = wt + ((size_t)e*H2X + j0 + 64 + rA)*KDIM + gb;
  const uint8_t* g0p = wt + ((size_t)e*H2X + INNER + j0 + rA)*KDIM + gb;
  const uint8_t* g1p = wt + ((size_t)e*H2X + INNER + j0 + 64 + rA)*KDIM + gb;
  floatx4 aca[4][2], acg[4][2];
  #pragma unroll
  for(int i=0;i<4;i++)
    #pragma unroll
    for(int j=0;j<2;j++){ aca[i][j]=(floatx4){0.f,0.f,0.f,0.f}; acg[i][j]=(floatx4){0.f,0.f,0.f,0.f}; }
  int ldsw = wid*1024;

  auto stage = [&](int kt, uint8_t* dA, uint8_t* dBa, uint8_t* dBg){
    gload16(a0p + kt, dA + ldsw);
    gload16(b0p + kt, dBa + ldsw);
    gload16(b1p + kt, dBa + 4096 + ldsw);
    gload16(g0p + kt, dBg + ldsw);
    gload16(g1p + kt, dBg + 4096 + ldsw);
  };
  auto compute = [&](const uint8_t* cA, const uint8_t* cBa, const uint8_t* cBg){
    #pragma unroll
    for(int s=0;s<2;s++){
      int pq = (((s*4+quad) ^ (l15&6)))*8;
      long af[4], ba[2], bg[2];
      #pragma unroll
      for(int mi=0;mi<4;mi++) af[mi] = *(const long*)&cA[(mi*16+l15)*64 + pq];
      #pragma unroll
      for(int ni=0;ni<2;ni++){
        int col = wid*32 + ni*16 + l15;
        ba[ni] = *(const long*)&cBa[col*64 + pq];
        bg[ni] = *(const long*)&cBg[col*64 + pq];
      }
      #pragma unroll
      for(int mi=0;mi<4;mi++)
        #pragma unroll
        for(int ni=0;ni<2;ni++){
          aca[mi][ni] = __builtin_amdgcn_mfma_f32_16x16x32_fp8_fp8(af[mi], ba[ni], aca[mi][ni],0,0,0);
          acg[mi][ni] = __builtin_amdgcn_mfma_f32_16x16x32_fp8_fp8(af[mi], bg[ni], acg[mi][ni],0,0,0);
        }
    }
  };

  stage(0, sA0, sBa0, sBg0);
  __syncthreads();
  for(int kt=0; kt<KDIM; kt+=128){
    if (kt+64 < KDIM) stage(kt+64, sA1, sBa1, sBg1);
    compute(sA0, sBa0, sBg0);
    __syncthreads();
    if (kt+128 < KDIM) stage(kt+128, sA0, sBa0, sBg0);
    compute(sA1, sBa1, sBg1);
    __syncthreads();
  }

  #pragma unroll
  for(int ni=0;ni<2;ni++){
    int j = j0 + wid*32 + ni*16 + l15;
    float ba_ = bias[e*H2X + j];
    float bg_ = bias[e*H2X + INNER + j];
    #pragma unroll
    for(int mi=0;mi<4;mi++){
      int rl = mi*16 + quad*4;
      #pragma unroll
      for(int r=0;r<4;r++){
        int row = mtile*64 + rl + r;
        if(row < cn){
          float a = aca[mi][ni][r]*inv_scale + ba_;
          float g = acg[mi][ni][r]*inv_scale + bg_;
          out[(size_t)(base+row)*INNER + j] = f2fp8(a*g*fsigmoid(g)*out_scale);
        }
      }
    }
  }
}

#define SG_NX (INNER/128)
#define SG_NY (NN/64)
__global__ __launch_bounds__(256,3) void gemm_sg1_kernel(
    const uint8_t* __restrict__ A, const uint8_t* __restrict__ wt,
    const float* __restrict__ bias, const int* __restrict__ cnt, uint8_t* __restrict__ out){
  int id = blockIdx.x;
  int y = id % SG_NY, xe = id / SG_NY;
  gemm_swiglu_impl<DIM>(A, wt, bias, cnt, out, 1.f/64.f, 64.f, xe % SG_NX, y, xe / SG_NX);
}
__global__ __launch_bounds__(256,3) void gemm_sg2_kernel(
    const uint8_t* __restrict__ A, const uint8_t* __restrict__ wt,
    const float* __restrict__ bias, const int* __restrict__ cnt, uint8_t* __restrict__ out){
  int id = blockIdx.x;
  int y = id % SG_NY, xe = id / SG_NY;
  gemm_swiglu_impl<INNER>(A, wt, bias, cnt, out, 1.f/512.f, 2097152.f, xe % SG_NX, y, xe / SG_NX);
}

// ---------------- fp8 expert output GEMM, split-K=2 -> two eo slabs ----------------
// Exact R4 form: M=64 tile, 4 waves in 1x4 over N=128; acc = 32 AGPR.
__global__ __launch_bounds__(256,4) void gemm_out_kernel(
    const uint8_t* __restrict__ h2, const uint8_t* __restrict__ w3t,
    const float* __restrict__ be3, const int* __restrict__ cnt, float* __restrict__ eo){
  int e = blockIdx.z;
  int cn = cnt[e];
  int mtile = blockIdx.y;
  if (mtile*64 >= cn) return;
  int base = prefix_cnt(cnt, e);
  int jt = blockIdx.x % 3, kh = blockIdx.x / 3;
  int n0 = jt*128;
  int koff = kh*768;
  float* eos = eo + (size_t)kh*NASSIGN*DIM;
  int tid=threadIdx.x, lane=tid&63, wid=tid>>6;
  int l15=lane&15, quad=lane>>4;
  __shared__ alignas(16) uint8_t sA0[64*64];
  __shared__ alignas(16) uint8_t sA1[64*64];
  __shared__ alignas(16) uint8_t sB0[128*64];
  __shared__ alignas(16) uint8_t sB1[128*64];
  int rA = tid>>2;
  int gb = ((tid&3) ^ ((tid>>3)&3))*16;
  const uint8_t* a0p = h2 + (size_t)(base + min(mtile*64+rA, cn-1))*INNER + koff + gb;
  const uint8_t* b0p = w3t + ((size_t)e*DIM + n0 + rA)*INNER + koff + gb;
  const uint8_t* b1p = w3t + ((size_t)e*DIM + n0 + 64 + rA)*INNER + koff + gb;
  floatx4 acc[4][2];
  #pragma unroll
  for(int i=0;i<4;i++)
    #pragma unroll
    for(int j=0;j<2;j++) acc[i][j]=(floatx4){0.f,0.f,0.f,0.f};
  int ldsw = wid*1024;

  auto stage = [&](int kt, uint8_t* dA, uint8_t* dB){
    gload16(a0p + kt, dA + ldsw);
    gload16(b0p + kt, dB + ldsw);
    gload16(b1p + kt, dB + 4096 + ldsw);
  };
  auto compute = [&](const uint8_t* cA, const uint8_t* cB){
    #pragma unroll
    for(int s=0;s<2;s++){
      int pq = (((s*4+quad) ^ (l15&6)))*8;
      long af[4], bfr[2];
      #pragma unroll
      for(int mi=0;mi<4;mi++) af[mi] = *(const long*)&cA[(mi*16+l15)*64 + pq];
      #pragma unroll
      for(int ni=0;ni<2;ni++){
        int col = wid*32 + ni*16 + l15;
        bfr[ni] = *(const long*)&cB[col*64 + pq];
      }
      #pragma unroll
      for(int mi=0;mi<4;mi++)
        #pragma unroll
        for(int ni=0;ni<2;ni++)
          acc[mi][ni] = __builtin_amdgcn_mfma_f32_16x16x32_fp8_fp8(af[mi], bfr[ni], acc[mi][ni],0,0,0);
    }
  };

  stage(0, sA0, sB0);
  __syncthreads();
  for(int kt=0; kt<768; kt+=128){
    if (kt+64 < 768) stage(kt+64, sA1, sB1);
    compute(sA0, sB0);
    __syncthreads();
    if (kt+128 < 768) stage(kt+128, sA0, sB0);
    compute(sA1, sB1);
    __syncthreads();
  }

  const float OSC = 5.9604644775390625e-8f;  // 2^-24
  #pragma unroll
  for(int ni=0;ni<2;ni++){
    int col = n0 + wid*32 + ni*16 + l15;
    float b3 = (kh==0) ? be3[e*DIM + col] : 0.f;
    #pragma unroll
    for(int mi=0;mi<4;mi++){
      int rl = mi*16 + quad*4;
      #pragma unroll
      for(int r=0;r<4;r++){
        int row = mtile*64 + rl + r;
        if(row < cn){
          eos[(size_t)(base+row)*DIM + col] = acc[mi][ni][r]*OSC + b3;
        }
      }
    }
  }
}

// ---------------- combine expert outputs + pooled accumulation ----------------
__global__ __launch_bounds__(384) void combine_pooled_kernel(const float* __restrict__ eo,
    const int* __restrict__ inv, const float* __restrict__ rwt,
    const float* __restrict__ x, const float* __restrict__ sres,
    float* __restrict__ y, float* __restrict__ pooled){
  int b = blockIdx.y, t0 = blockIdx.x*8;
  int d = threadIdx.x;
  const float* eo1 = eo + (size_t)NASSIGN*DIM;
  float sr = sres[d];
  float acc = 0.f;
  for(int t=0;t<8;t++){
    int n = b*NT + t0 + t;
    int p0 = inv[2*n], p1 = inv[2*n+1];
    float w0 = rwt[2*n], w1 = rwt[2*n+1];
    size_t o = (size_t)n*DIM + d;
    float yv = y[o] + w0*(eo[(size_t)p0*DIM+d] + eo1[(size_t)p0*DIM+d])
                    + w1*(eo[(size_t)p1*DIM+d] + eo1[(size_t)p1*DIM+d]);
    y[o] = yv;
    acc += x[o]*sr + yv;
  }
  atomicAdd(&pooled[b*DIM+d], acc*(1.f/NT));
}

// ---------------- fused gate + final ----------------
__global__ __launch_bounds__(384) void gatefinal_kernel(const float* __restrict__ pooled,
    const float* __restrict__ sw1, const float* __restrict__ sb1,
    const float* __restrict__ sw2, const float* __restrict__ sb2,
    const float* __restrict__ res, const float* __restrict__ y, float* __restrict__ out){
  int b = blockIdx.y, t0 = blockIdx.x*8;
  int d = threadIdx.x;
  __shared__ float sp[DIM];
  __shared__ float sh[SQZ];
  sp[d] = pooled[b*DIM+d];
  __syncthreads();
  if(d<SQZ){
    float a = sb1[d];
    for(int k=0;k<DIM;k++) a += sp[k]*sw1[k*SQZ+d];
    sh[d] = a*fsigmoid(a);
  }
  __syncthreads();
  float a = sb2[d];
  #pragma unroll
  for(int j=0;j<SQZ;j++) a += sh[j]*sw2[j*DIM+d];
  float g = fsigmoid(a);
  for(int t=0;t<8;t++){
    size_t o = ((size_t)b*NT + t0 + t)*DIM + d;
    out[o] = res[o] + y[o]*g;
  }
}

extern "C" void kernel_launch(void* const* d_in, const int* in_sizes, int n_in,
                              void* d_out, int out_size, void* d_ws, size_t ws_size,
                              hipStream_t stream) {
  (void)in_sizes; (void)n_in; (void)out_size; (void)ws_size;
  const float* res   = (const float*)d_in[0];
  const float* ln_g  = (const float*)d_in[1];
  const float* ln_b  = (const float*)d_in[2];
  const float* conv_w= (const float*)d_in[3];
  const float* conv_b= (const float*)d_in[4];
  const float* rw1   = (const float*)d_in[5];
  const float* rb1   = (const float*)d_in[6];
  const float* rw2   = (const float*)d_in[7];
  const float* rb2   = (const float*)d_in[8];
  const float* we1   = (const float*)d_in[9];
  const float* be1   = (const float*)d_in[10];
  const float* we2   = (const float*)d_in[11];
  const float* be2   = (const float*)d_in[12];
  const float* we3   = (const float*)d_in[13];
  const float* be3   = (const float*)d_in[14];
  const float* sw1   = (const float*)d_in[15];
  const float* sb1   = (const float*)d_in[16];
  const float* sw2   = (const float*)d_in[17];
  const float* sb2   = (const float*)d_in[18];
  const float* sres  = (const float*)d_in[19];
  float* out = (float*)d_out;

  char* ws = (char*)d_ws;
  size_t off = 0;
  auto alloc = [&](size_t bytes)->void*{ void* p = ws + off; off = (off + bytes + 255) & ~(size_t)255; return p; };
  float*          x     = (float*)alloc((size_t)NN*DIM*4);
  float*          y     = (float*)alloc((size_t)NN*DIM*4);
  float*          eo    = (float*)alloc((size_t)2*NASSIGN*DIM*4);
  unsigned short* tokb  = (unsigned short*)alloc((size_t)NN*DIM*2);
  uint8_t*        tokc  = (uint8_t*)alloc((size_t)NASSIGN*DIM);
  unsigned short* g1    = (unsigned short*)alloc((size_t)NN*DIM*2);
  uint8_t*        w1t   = (uint8_t*)alloc((size_t)NE*H2X*DIM);
  uint8_t*        w2t   = (uint8_t*)alloc((size_t)NE*H2X*INNER);
  uint8_t*        w3t   = (uint8_t*)alloc((size_t)NE*DIM*INNER);
  unsigned short* rw1t  = (unsigned short*)alloc((size_t)DIM*DIM*2);
  uint8_t*        h1    = (uint8_t*)alloc((size_t)NASSIGN*INNER);
  uint8_t*        h2b   = (uint8_t*)alloc((size_t)NASSIGN*INNER);
  int*            ridx  = (int*)alloc((size_t)NASSIGN*4);
  float*          rwt   = (float*)alloc((size_t)NASSIGN*4);
  int*            inv   = (int*)alloc((size_t)NASSIGN*4);
  int*            cnt   = (int*)alloc(128);
  int*            cnt2  = cnt + 8;
  float*          pooled= (float*)alloc((size_t)NB*DIM*4);

  tr_all_kernel<<<TR_N1+TR_N2+TR_N3+TR_N4, dim3(32,8), 0, stream>>>(
      we1, w1t, we2, w2t, we3, w3t, rw1, rw1t);
  convln_kernel<<<dim3(NT/CTT, NB), 384, 0, stream>>>(
      res, ln_g, ln_b, conv_w, conv_b, x, tokb, y);
  router_g1_kernel<<<dim3(DIM/128, NN/128), 256, 0, stream>>>(tokb, rw1t, rb1, g1, cnt);
  router2_kernel<<<NN/32, 256, 0, stream>>>(g1, rw2, rb2, ridx, rwt, cnt);
  fillcompact_kernel<<<NASSIGN/32, 256, 0, stream>>>(ridx, cnt, cnt2, inv, tokb, tokc, pooled);

  gemm_sg1_kernel<<<SG_NX*SG_NY*NE, 256, 0, stream>>>(tokc, w1t, be1, cnt, h1);
  gemm_sg2_kernel<<<SG_NX*SG_NY*NE, 256, 0, stream>>>(h1, w2t, be2, cnt, h2b);
  gemm_out_kernel<<<dim3(6, NN/64, NE), 256, 0, stream>>>(h2b, w3t, be3, cnt, eo);
  combine_pooled_kernel<<<dim3(NT/8, NB), 384, 0, stream>>>(
      eo, inv, rwt, x, sres, y, pooled);
  gatefinal_kernel<<<dim3(NT/8, NB), 384, 0, stream>>>(
      pooled, sw1, sb1, sw2, sb2, res, y, out);
}

// Round 10
// 430.276 us; speedup vs baseline: 1.1065x; 1.0580x over previous
//
#include <hip/hip_runtime.h>
#include <stdint.h>

#define DIM 384
#define INNER 1536
#define H2X 3072
#define NE 5
#define NB 4
#define NT 1024
#define NN (NB*NT)
#define KSZ 31
#define SQZ 48
#define NASSIGN (NN*2)

typedef float floatx4 __attribute__((ext_vector_type(4)));
typedef __bf16 bf16x8 __attribute__((ext_vector_type(8)));

__device__ __forceinline__ unsigned short f2bs(float f){
  union { float f; uint32_t u; } v; v.f = f;
  uint32_t r = (v.u + 0x7fffu + ((v.u >> 16) & 1u)) >> 16;
  return (unsigned short)r;
}
__device__ __forceinline__ float bs2f(unsigned short s){
  union { uint32_t u; float f; } v; v.u = ((uint32_t)s) << 16; return v.f;
}
__device__ __forceinline__ float fsigmoid(float x){ return 1.f/(1.f+__expf(-x)); }

__device__ __forceinline__ uint32_t pk2_lo(float a, float b, uint32_t old){
  return __builtin_amdgcn_cvt_pk_fp8_f32(a, b, old, false);
}
__device__ __forceinline__ uint32_t pk2_hi(float a, float b, uint32_t old){
  return __builtin_amdgcn_cvt_pk_fp8_f32(a, b, old, true);
}
__device__ __forceinline__ uint8_t f2fp8(float a){
  return (uint8_t)__builtin_amdgcn_cvt_pk_fp8_f32(a, 0.f, 0u, false);
}

__device__ __forceinline__ void gload16(const void* g, void* l){
  __builtin_amdgcn_global_load_lds(
    reinterpret_cast<const __attribute__((address_space(1))) unsigned int*>(
        reinterpret_cast<uintptr_t>(g)),
    reinterpret_cast<__attribute__((address_space(3))) unsigned int*>(
        (unsigned int)reinterpret_cast<uintptr_t>(l)),
    16, 0, 0);
}

__device__ __forceinline__ int prefix_cnt(const int* __restrict__ cnt, int e){
  int base = 0;
  #pragma unroll
  for(int k=0;k<NE;k++) base += (k<e) ? cnt[k] : 0;
  return base;
}

#define WSCALE 8.f

// ---------------- weight transposes (one dispatch) ----------------
__device__ __forceinline__ void do_tr_bf16(const float* __restrict__ in,
    unsigned short* __restrict__ out, int R, int C, int cx, int cy){
  __shared__ float tile[32][65];
  int c0 = cx*32, r0 = cy*64;
  int tx = threadIdx.x, ty = threadIdx.y;
  #pragma unroll
  for (int i=0;i<8;i++){
    int r = ty + i*8;
    tile[tx][r] = in[(size_t)(r0+r)*C + c0 + tx];
  }
  __syncthreads();
  #pragma unroll
  for (int i=0;i<4;i++){
    int c = ty + i*8;
    uint32_t lo = f2bs(tile[c][2*tx]);
    uint32_t hi = f2bs(tile[c][2*tx+1]);
    *(uint32_t*)&out[(size_t)(c0+c)*R + r0 + 2*tx] = lo | (hi<<16);
  }
}
__device__ __forceinline__ void do_tr_fp8(const float* __restrict__ in,
    uint8_t* __restrict__ out, int R, int C, int cx, int cy){
  __shared__ float tile[32][65];
  int c0 = cx*32, r0 = cy*64;
  int tx = threadIdx.x, ty = threadIdx.y;
  #pragma unroll
  for (int i=0;i<8;i++){
    int r = ty + i*8;
    tile[tx][r] = in[(size_t)(r0+r)*C + c0 + tx];
  }
  __syncthreads();
  #pragma unroll
  for (int i=0;i<4;i++){
    int c = ty + i*8;
    uint32_t v = pk2_lo(tile[c][2*tx]*WSCALE, tile[c][2*tx+1]*WSCALE, 0u);
    *(unsigned short*)&out[(size_t)(c0+c)*R + r0 + 2*tx] = (unsigned short)(v & 0xffffu);
  }
}

#define TR_N1 (96*6*5)
#define TR_N2 (96*24*5)
#define TR_N3 (12*24*5)
#define TR_N4 (12*6)
__global__ __launch_bounds__(256) void tr_all_kernel(
    const float* __restrict__ we1, uint8_t* __restrict__ w1t,
    const float* __restrict__ we2, uint8_t* __restrict__ w2t,
    const float* __restrict__ we3, uint8_t* __restrict__ w3t,
    const float* __restrict__ rw1, unsigned short* __restrict__ rw1t){
  int bid = blockIdx.x;
  if (bid < TR_N1){
    int z = bid/(96*6), rem = bid%(96*6);
    do_tr_fp8(we1 + (size_t)z*384*3072, w1t + (size_t)z*384*3072, 384, 3072, rem%96, rem/96);
  } else if (bid < TR_N1+TR_N2){
    int idx = bid - TR_N1;
    int z = idx/(96*24), rem = idx%(96*24);
    do_tr_fp8(we2 + (size_t)z*1536*3072, w2t + (size_t)z*1536*3072, 1536, 3072, rem%96, rem/96);
  } else if (bid < TR_N1+TR_N2+TR_N3){
    int idx = bid - TR_N1 - TR_N2;
    int z = idx/(12*24), rem = idx%(12*24);
    do_tr_fp8(we3 + (size_t)z*1536*384, w3t + (size_t)z*1536*384, 1536, 384, rem%12, rem/12);
  } else {
    int idx = bid - TR_N1 - TR_N2 - TR_N3;
    do_tr_bf16(rw1, rw1t, 384, 384, idx%12, idx/12);
  }
}

// ---------------- fused LayerNorm + depthwise conv ----------------
// Sliding-window conv: 46-row register window (46 LDS reads/thread vs 496).
#define CTT 16
__global__ __launch_bounds__(384) void convln_kernel(const float* __restrict__ res,
    const float* __restrict__ ln_g, const float* __restrict__ ln_b,
    const float* __restrict__ cw, const float* __restrict__ cb,
    float* __restrict__ x, unsigned short* __restrict__ tokb, float* __restrict__ y){
  __shared__ float tile[(CTT+30)*DIM];
  int b = blockIdx.y, t0 = blockIdx.x*CTT;
  int tid = threadIdx.x;
  int w = tid>>6, lane = tid&63;
  float gw[6], bw[6];
  #pragma unroll
  for(int i=0;i<6;i++){ gw[i]=ln_g[i*64+lane]; bw[i]=ln_b[i*64+lane]; }
  for(int r=w; r<CTT+30; r+=6){
    int gt = t0 - 15 + r;
    if(gt>=0 && gt<NT){
      const float* rp = res + ((size_t)b*NT+gt)*DIM;
      float v[6]; float s=0.f;
      #pragma unroll
      for(int i=0;i<6;i++){ v[i]=rp[i*64+lane]; s+=v[i]; }
      #pragma unroll
      for(int o=32;o;o>>=1) s += __shfl_down(s,o);
      s = __shfl(s,0);
      float mean = s*(1.f/DIM);
      float q=0.f;
      #pragma unroll
      for(int i=0;i<6;i++){ v[i]-=mean; q+=v[i]*v[i]; }
      #pragma unroll
      for(int o=32;o;o>>=1) q += __shfl_down(q,o);
      q = __shfl(q,0);
      float rstd = rsqrtf(q*(1.f/DIM) + 1e-5f);
      #pragma unroll
      for(int i=0;i<6;i++) tile[r*DIM+i*64+lane] = v[i]*rstd*gw[i]+bw[i];
    } else {
      #pragma unroll
      for(int i=0;i<6;i++) tile[r*DIM+i*64+lane] = 0.f;
    }
  }
  __syncthreads();
  float cwr[KSZ];
  #pragma unroll
  for(int k=0;k<KSZ;k++) cwr[k] = cw[tid*KSZ+k];
  float bias = cb[tid];
  float win[CTT+30];
  #pragma unroll
  for(int r=0;r<CTT+30;r++) win[r] = tile[r*DIM+tid];
  #pragma unroll
  for(int t=0;t<CTT;t++){
    float acc = bias;
    #pragma unroll
    for(int k=0;k<KSZ;k++) acc += win[t+k]*cwr[k];
    size_t o = ((size_t)b*NT + t0 + t)*DIM + tid;
    y[o]=acc; tokb[o]=f2bs(acc);
    x[o]=win[t+15];
  }
}

// ---------------- router GEMM1 (bf16; also zeroes cnt/cnt2) ----------------
__global__ __launch_bounds__(256) void router_g1_kernel(const unsigned short* __restrict__ tokb,
    const unsigned short* __restrict__ rw1t, const float* __restrict__ rb1,
    unsigned short* __restrict__ g1, int* __restrict__ cnt){
  int tid = threadIdx.x;
  if(blockIdx.x==0 && blockIdx.y==0 && tid<32) cnt[tid]=0;
  __shared__ alignas(16) unsigned short sA0[128*32];
  __shared__ alignas(16) unsigned short sA1[128*32];
  __shared__ alignas(16) unsigned short sB0[128*32];
  __shared__ alignas(16) unsigned short sB1[128*32];
  int n0 = blockIdx.x*128, m0 = blockIdx.y*128;
  int lane = tid&63, wid = tid>>6, wm = wid&1, wn = wid>>1;
  int l15 = lane&15, quad = lane>>4;
  floatx4 acc[4][4];
  #pragma unroll
  for(int i=0;i<4;i++)
    #pragma unroll
    for(int j=0;j<4;j++) acc[i][j]=(floatx4){0.f,0.f,0.f,0.f};
  int rA = tid>>2, c8 = tid&3;
  const unsigned short* a0p = tokb + (size_t)(m0+rA)*DIM;
  const unsigned short* a1p = tokb + (size_t)(m0+64+rA)*DIM;
  const unsigned short* b0p = rw1t + (size_t)(n0+rA)*DIM;
  const unsigned short* b1p = rw1t + (size_t)(n0+64+rA)*DIM;

  auto stage = [&](int kt, unsigned short* dA, unsigned short* dB){
    gload16(a0p + kt + c8*8, dA + wid*512);
    gload16(a1p + kt + c8*8, dA + 2048 + wid*512);
    gload16(b0p + kt + c8*8, dB + wid*512);
    gload16(b1p + kt + c8*8, dB + 2048 + wid*512);
  };
  auto compute = [&](const unsigned short* cA, const unsigned short* cB){
    bf16x8 af[4], bfr[4];
    #pragma unroll
    for(int mi=0;mi<4;mi++) af[mi] = *(const bf16x8*)&cA[(wm*64+mi*16+l15)*32 + quad*8];
    #pragma unroll
    for(int ni=0;ni<4;ni++) bfr[ni] = *(const bf16x8*)&cB[(wn*64+ni*16+l15)*32 + quad*8];
    #pragma unroll
    for(int mi=0;mi<4;mi++)
      #pragma unroll
      for(int ni=0;ni<4;ni++)
        acc[mi][ni] = __builtin_amdgcn_mfma_f32_16x16x32_bf16(af[mi], bfr[ni], acc[mi][ni],0,0,0);
  };

  stage(0, sA0, sB0);
  __syncthreads();
  for(int kt=0; kt<DIM; kt+=64){
    if (kt+32 < DIM) stage(kt+32, sA1, sB1);
    compute(sA0, sB0);
    __syncthreads();
    if (kt+64 < DIM) stage(kt+64, sA0, sB0);
    compute(sA1, sB1);
    __syncthreads();
  }
  #pragma unroll
  for(int ni=0;ni<4;ni++){
    int col = n0 + wn*64 + ni*16 + l15;
    float bias = rb1[col];
    #pragma unroll
    for(int mi=0;mi<4;mi++){
      int rowb = m0 + wm*64 + mi*16 + quad*4;
      #pragma unroll
      for(int r=0;r<4;r++){
        float v = acc[mi][ni][r] + bias;
        g1[(size_t)(rowb+r)*DIM + col] = f2bs(v*fsigmoid(v));
      }
    }
  }
}

// ---------------- router2 ----------------
// Block covers 32 tokens; LDS histogram; one global atomic per expert per
// block (640 total vs 8192 same-line contended atomics = ~97 us idle).
__global__ __launch_bounds__(256) void router2_kernel(const unsigned short* __restrict__ g1,
    const float* __restrict__ rw2, const float* __restrict__ rb2,
    int* __restrict__ ridx, float* __restrict__ rwt, int* __restrict__ cnt){
  __shared__ int hist[8];
  int tid = threadIdx.x;
  int wid = tid>>6, lane = tid&63;
  if(tid<8) hist[tid]=0;
  __syncthreads();
  for(int it=0; it<8; ++it){
    int n = blockIdx.x*32 + wid*8 + it;
    float s[NE]={0.f,0.f,0.f,0.f,0.f};
    #pragma unroll
    for(int i=0;i<6;i++){
      int d = lane + i*64;
      float gv = bs2f(g1[(size_t)n*DIM+d]);
      #pragma unroll
      for(int e=0;e<NE;e++) s[e] += gv * rw2[d*NE+e];
    }
    #pragma unroll
    for(int e=0;e<NE;e++)
      #pragma unroll
      for(int o=32;o;o>>=1) s[e] += __shfl_down(s[e],o);
    if(lane==0){
      float r[NE];
      #pragma unroll
      for(int e=0;e<NE;e++) r[e]=s[e]+rb2[e];
      int e0=0;
      for(int e=1;e<NE;e++) if(r[e]>r[e0]) e0=e;
      int e1=-1;
      for(int e=0;e<NE;e++){ if(e==e0) continue; if(e1<0||r[e]>r[e1]) e1=e; }
      float w0 = 1.f/(1.f+__expf(r[e1]-r[e0]));
      ridx[2*n]=e0; ridx[2*n+1]=e1;
      rwt[2*n]=w0; rwt[2*n+1]=1.f-w0;
      atomicAdd(&hist[e0],1); atomicAdd(&hist[e1],1);
    }
  }
  __syncthreads();
  if(tid<NE) atomicAdd(&cnt[tid], hist[tid]);
}

// ---------------- fill positions + compact tokens to fp8 (x8) + zero pooled ----------------
// 512 blocks x 32 assignments: wave-0 ballot rank (lanes>=32 carry e=-1),
// one returning atomic per expert per wave; copy = 8 rows/wave across chip.
__global__ __launch_bounds__(256) void fillcompact_kernel(const int* __restrict__ ridx,
    const int* __restrict__ cnt, int* __restrict__ cnt2,
    int* __restrict__ inv, const unsigned short* __restrict__ tokb,
    uint8_t* __restrict__ tokc, float* __restrict__ pooled){
  __shared__ int sSrc[32], sPos[32];
  int tid = threadIdx.x;
  if(blockIdx.x==0){
    for(int i=tid;i<NB*DIM;i+=256) pooled[i]=0.f;
  }
  int lane = tid&63;
  if(tid<64){
    int i = blockIdx.x*32 + lane;
    int e = (lane<32) ? ridx[i] : -1;
    int base = (lane<32) ? prefix_cnt(cnt, e) : 0;
    unsigned long long below = (1ull<<lane)-1ull;
    int pos = 0;
    #pragma unroll
    for(int ex=0; ex<NE; ex++){
      unsigned long long m = __ballot(e==ex);
      if(m){
        int ldr = __ffsll((long long)m)-1;
        int nb = 0;
        if(lane==ldr) nb = atomicAdd(&cnt2[ex], (int)__popcll(m));
        nb = __shfl(nb, ldr);
        if(e==ex) pos = base + nb + (int)__popcll(m & below);
      }
    }
    if(lane<32){
      inv[i] = pos;
      sSrc[lane] = i>>1;
      sPos[lane] = pos;
    }
  }
  __syncthreads();
  int w = tid>>6;
  for(int j=0;j<8;j++){
    int idx = w*8+j;
    int src = sSrc[idx], dst = sPos[idx];
    if(lane<48){
      uint4 sv = ((const uint4*)&tokb[(size_t)src*DIM])[lane];
      float f0=bs2f(sv.x&0xffff)*WSCALE, f1=bs2f(sv.x>>16)*WSCALE;
      float f2=bs2f(sv.y&0xffff)*WSCALE, f3=bs2f(sv.y>>16)*WSCALE;
      float f4=bs2f(sv.z&0xffff)*WSCALE, f5=bs2f(sv.z>>16)*WSCALE;
      float f6=bs2f(sv.w&0xffff)*WSCALE, f7=bs2f(sv.w>>16)*WSCALE;
      uint32_t lo = pk2_hi(f2,f3, pk2_lo(f0,f1,0u));
      uint32_t hi = pk2_hi(f6,f7, pk2_lo(f4,f5,0u));
      uint2 pv; pv.x = lo; pv.y = hi;
      ((uint2*)&tokc[(size_t)dst*DIM])[lane] = pv;
    }
  }
}

// ---------------- fp8 expert GEMM + fused SwiGLU ----------------
// Measured-best Round-4 structure (M=64, 1x4 waves, A+B LDS, b64 frag reads,
// 2D grid x-fastest — all alternatives R5-R9 regressed). ONE change: counted
// vmcnt across the barrier (T4). Per 64-K phase: stage(t+1) -> vmcnt(5)
// (tile-t's 5 loads retired in-order, t+1's 5 stay IN FLIGHT across the
// barrier) -> s_barrier -> compute(t) -> s_barrier. Removes the per-phase
// vmcnt(0) drain of just-issued loads (the exposed L2/L3 queuing latency)
// at the cost of one extra cheap barrier. Same LDS (40KB) -> 4 blocks/CU,
// same register budget (64 VGPR + 64 AGPR = 128 -> 4 waves/SIMD).
template<int KDIM>
__device__ __forceinline__ void gemm_swiglu_impl(
    const uint8_t* __restrict__ A,
    const uint8_t* __restrict__ wt, const float* __restrict__ bias,
    const int* __restrict__ cnt, uint8_t* __restrict__ out,
    float inv_scale, float out_scale){
  int e = blockIdx.z;
  int cn = cnt[e];
  int mtile = blockIdx.y;
  if (mtile*64 >= cn) return;
  int base = prefix_cnt(cnt, e);
  int j0 = blockIdx.x*128;
  int tid=threadIdx.x, lane=tid&63, wid=tid>>6;
  int l15=lane&15, quad=lane>>4;
  __shared__ alignas(16) uint8_t sA0[64*64];
  __shared__ alignas(16) uint8_t sA1[64*64];
  __shared__ alignas(16) uint8_t sBa0[128*64];
  __shared__ alignas(16) uint8_t sBa1[128*64];
  __shared__ alignas(16) uint8_t sBg0[128*64];
  __shared__ alignas(16) uint8_t sBg1[128*64];
  int rA = tid>>2;
  int gb = ((tid&3) ^ ((tid>>3)&3))*16;   // swizzled global chunk offset
  const uint8_t* a0p = A + (size_t)(base + min(mtile*64+rA, cn-1))*KDIM + gb;
  const uint8_t* b0p = wt + ((size_t)e*H2X + j0 + rA)*KDIM + gb;
  const uint8_t* b1p = wt + ((size_t)e*H2X + j0 + 64 + rA)*KDIM + gb;
  const uint8_t* g0p = wt + ((size_t)e*H2X + INNER + j0 + rA)*KDIM + gb;
  const uint8_t* g1p = wt + ((size_t)e*H2X + INNER + j0 + 64 + rA)*KDIM + gb;
  floatx4 aca[4][2], acg[4][2];
  #pragma unroll
  for(int i=0;i<4;i++)
    #pragma unroll
    for(int j=0;j<2;j++){ aca[i][j]=(floatx4){0.f,0.f,0.f,0.f}; acg[i][j]=(floatx4){0.f,0.f,0.f,0.f}; }
  int ldsw = wid*1024;

  auto stage = [&](int kt, uint8_t* dA, uint8_t* dBa, uint8_t* dBg){
    gload16(a0p + kt, dA + ldsw);
    gload16(b0p + kt, dBa + ldsw);
    gload16(b1p + kt, dBa + 4096 + ldsw);
    gload16(g0p + kt, dBg + ldsw);
    gload16(g1p + kt, dBg + 4096 + ldsw);
  };
  auto compute = [&](const uint8_t* cA, const uint8_t* cBa, const uint8_t* cBg){
    #pragma unroll
    for(int s=0;s<2;s++){
      int pq = (((s*4+quad) ^ (l15&6)))*8;
      long af[4], ba[2], bg[2];
      #pragma unroll
      for(int mi=0;mi<4;mi++) af[mi] = *(const long*)&cA[(mi*16+l15)*64 + pq];
      #pragma unroll
      for(int ni=0;ni<2;ni++){
        int col = wid*32 + ni*16 + l15;
        ba[ni] = *(const long*)&cBa[col*64 + pq];
        bg[ni] = *(const long*)&cBg[col*64 + pq];
      }
      #pragma unroll
      for(int mi=0;mi<4;mi++)
        #pragma unroll
        for(int ni=0;ni<2;ni++){
          aca[mi][ni] = __builtin_amdgcn_mfma_f32_16x16x32_fp8_fp8(af[mi], ba[ni], aca[mi][ni],0,0,0);
          acg[mi][ni] = __builtin_amdgcn_mfma_f32_16x16x32_fp8_fp8(af[mi], bg[ni], acg[mi][ni],0,0,0);
        }
    }
  };

  constexpr int nt = KDIM/64;   // 6 (sg1) or 24 (sg2), both even
  stage(0, sA0, sBa0, sBg0);
  #pragma unroll 1
  for(int t=0; t<nt; t+=2){
    // phase t (buf0): stage t+1 (always valid: nt even, t even)
    stage((t+1)*64, sA1, sBa1, sBg1);
    asm volatile("s_waitcnt vmcnt(5)" ::: "memory");   // tile-t landed; t+1 in flight
    __builtin_amdgcn_s_barrier();
    compute(sA0, sBa0, sBg0);
    __builtin_amdgcn_s_barrier();                      // reads done before overwrite
    // phase t+1 (buf1): stage t+2 if any
    if (t+2 < nt){
      stage((t+2)*64, sA0, sBa0, sBg0);
      asm volatile("s_waitcnt vmcnt(5)" ::: "memory"); // tile-(t+1) landed
    } else {
      asm volatile("s_waitcnt vmcnt(0)" ::: "memory"); // final drain
    }
    __builtin_amdgcn_s_barrier();
    compute(sA1, sBa1, sBg1);
    __builtin_amdgcn_s_barrier();
  }

  #pragma unroll
  for(int ni=0;ni<2;ni++){
    int j = j0 + wid*32 + ni*16 + l15;
    float ba_ = bias[e*H2X + j];
    float bg_ = bias[e*H2X + INNER + j];
    #pragma unroll
    for(int mi=0;mi<4;mi++){
      int rl = mi*16 + quad*4;
      #pragma unroll
      for(int r=0;r<4;r++){
        int row = mtile*64 + rl + r;
        if(row < cn){
          float a = aca[mi][ni][r]*inv_scale + ba_;
          float g = acg[mi][ni][r]*inv_scale + bg_;
          out[(size_t)(base+row)*INNER + j] = f2fp8(a*g*fsigmoid(g)*out_scale);
        }
      }
    }
  }
}

__global__ __launch_bounds__(256,3) void gemm_sg1_kernel(
    const uint8_t* __restrict__ A, const uint8_t* __restrict__ wt,
    const float* __restrict__ bias, const int* __restrict__ cnt, uint8_t* __restrict__ out){
  gemm_swiglu_impl<DIM>(A, wt, bias, cnt, out, 1.f/64.f, 64.f);
}
__global__ __launch_bounds__(256,3) void gemm_sg2_kernel(
    const uint8_t* __restrict__ A, const uint8_t* __restrict__ wt,
    const float* __restrict__ bias, const int* __restrict__ cnt, uint8_t* __restrict__ out){
  gemm_swiglu_impl<INNER>(A, wt, bias, cnt, out, 1.f/512.f, 2097152.f);
}

// ---------------- fp8 expert output GEMM, split-K=2 -> two eo slabs ----------------
// Exact Round-4 form (control: keeps the syncthreads drain loop).
__global__ __launch_bounds__(256,4) void gemm_out_kernel(
    const uint8_t* __restrict__ h2, const uint8_t* __restrict__ w3t,
    const float* __restrict__ be3, const int* __restrict__ cnt, float* __restrict__ eo){
  int e = blockIdx.z;
  int cn = cnt[e];
  int mtile = blockIdx.y;
  if (mtile*64 >= cn) return;
  int base = prefix_cnt(cnt, e);
  int jt = blockIdx.x % 3, kh = blockIdx.x / 3;
  int n0 = jt*128;
  int koff = kh*768;
  float* eos = eo + (size_t)kh*NASSIGN*DIM;
  int tid=threadIdx.x, lane=tid&63, wid=tid>>6;
  int l15=lane&15, quad=lane>>4;
  __shared__ alignas(16) uint8_t sA0[64*64];
  __shared__ alignas(16) uint8_t sA1[64*64];
  __shared__ alignas(16) uint8_t sB0[128*64];
  __shared__ alignas(16) uint8_t sB1[128*64];
  int rA = tid>>2;
  int gb = ((tid&3) ^ ((tid>>3)&3))*16;
  const uint8_t* a0p = h2 + (size_t)(base + min(mtile*64+rA, cn-1))*INNER + koff + gb;
  const uint8_t* b0p = w3t + ((size_t)e*DIM + n0 + rA)*INNER + koff + gb;
  const uint8_t* b1p = w3t + ((size_t)e*DIM + n0 + 64 + rA)*INNER + koff + gb;
  floatx4 acc[4][2];
  #pragma unroll
  for(int i=0;i<4;i++)
    #pragma unroll
    for(int j=0;j<2;j++) acc[i][j]=(floatx4){0.f,0.f,0.f,0.f};
  int ldsw = wid*1024;

  auto stage = [&](int kt, uint8_t* dA, uint8_t* dB){
    gload16(a0p + kt, dA + ldsw);
    gload16(b0p + kt, dB + ldsw);
    gload16(b1p + kt, dB + 4096 + ldsw);
  };
  auto compute = [&](const uint8_t* cA, const uint8_t* cB){
    #pragma unroll
    for(int s=0;s<2;s++){
      int pq = (((s*4+quad) ^ (l15&6)))*8;
      long af[4], bfr[2];
      #pragma unroll
      for(int mi=0;mi<4;mi++) af[mi] = *(const long*)&cA[(mi*16+l15)*64 + pq];
      #pragma unroll
      for(int ni=0;ni<2;ni++){
        int col = wid*32 + ni*16 + l15;
        bfr[ni] = *(const long*)&cB[col*64 + pq];
      }
      #pragma unroll
      for(int mi=0;mi<4;mi++)
        #pragma unroll
        for(int ni=0;ni<2;ni++)
          acc[mi][ni] = __builtin_amdgcn_mfma_f32_16x16x32_fp8_fp8(af[mi], bfr[ni], acc[mi][ni],0,0,0);
    }
  };

  stage(0, sA0, sB0);
  __syncthreads();
  for(int kt=0; kt<768; kt+=128){
    if (kt+64 < 768) stage(kt+64, sA1, sB1);
    compute(sA0, sB0);
    __syncthreads();
    if (kt+128 < 768) stage(kt+128, sA0, sB0);
    compute(sA1, sB1);
    __syncthreads();
  }

  const float OSC = 5.9604644775390625e-8f;  // 2^-24
  #pragma unroll
  for(int ni=0;ni<2;ni++){
    int col = n0 + wid*32 + ni*16 + l15;
    float b3 = (kh==0) ? be3[e*DIM + col] : 0.f;
    #pragma unroll
    for(int mi=0;mi<4;mi++){
      int rl = mi*16 + quad*4;
      #pragma unroll
      for(int r=0;r<4;r++){
        int row = mtile*64 + rl + r;
        if(row < cn){
          eos[(size_t)(base+row)*DIM + col] = acc[mi][ni][r]*OSC + b3;
        }
      }
    }
  }
}

// ---------------- combine expert outputs + pooled accumulation ----------------
__global__ __launch_bounds__(384) void combine_pooled_kernel(const float* __restrict__ eo,
    const int* __restrict__ inv, const float* __restrict__ rwt,
    const float* __restrict__ x, const float* __restrict__ sres,
    float* __restrict__ y, float* __restrict__ pooled){
  int b = blockIdx.y, t0 = blockIdx.x*8;
  int d = threadIdx.x;
  const float* eo1 = eo + (size_t)NASSIGN*DIM;
  float sr = sres[d];
  float acc = 0.f;
  for(int t=0;t<8;t++){
    int n = b*NT + t0 + t;
    int p0 = inv[2*n], p1 = inv[2*n+1];
    float w0 = rwt[2*n], w1 = rwt[2*n+1];
    size_t o = (size_t)n*DIM + d;
    float yv = y[o] + w0*(eo[(size_t)p0*DIM+d] + eo1[(size_t)p0*DIM+d])
                    + w1*(eo[(size_t)p1*DIM+d] + eo1[(size_t)p1*DIM+d]);
    y[o] = yv;
    acc += x[o]*sr + yv;
  }
  atomicAdd(&pooled[b*DIM+d], acc*(1.f/NT));
}

// ---------------- fused gate + final ----------------
__global__ __launch_bounds__(384) void gatefinal_kernel(const float* __restrict__ pooled,
    const float* __restrict__ sw1, const float* __restrict__ sb1,
    const float* __restrict__ sw2, const float* __restrict__ sb2,
    const float* __restrict__ res, const float* __restrict__ y, float* __restrict__ out){
  int b = blockIdx.y, t0 = blockIdx.x*8;
  int d = threadIdx.x;
  __shared__ float sp[DIM];
  __shared__ float sh[SQZ];
  sp[d] = pooled[b*DIM+d];
  __syncthreads();
  if(d<SQZ){
    float a = sb1[d];
    for(int k=0;k<DIM;k++) a += sp[k]*sw1[k*SQZ+d];
    sh[d] = a*fsigmoid(a);
  }
  __syncthreads();
  float a = sb2[d];
  #pragma unroll
  for(int j=0;j<SQZ;j++) a += sh[j]*sw2[j*DIM+d];
  float g = fsigmoid(a);
  for(int t=0;t<8;t++){
    size_t o = ((size_t)b*NT + t0 + t)*DIM + d;
    out[o] = res[o] + y[o]*g;
  }
}

extern "C" void kernel_launch(void* const* d_in, const int* in_sizes, int n_in,
                              void* d_out, int out_size, void* d_ws, size_t ws_size,
                              hipStream_t stream) {
  (void)in_sizes; (void)n_in; (void)out_size; (void)ws_size;
  const float* res   = (const float*)d_in[0];
  const float* ln_g  = (const float*)d_in[1];
  const float* ln_b  = (const float*)d_in[2];
  const float* conv_w= (const float*)d_in[3];
  const float* conv_b= (const float*)d_in[4];
  const float* rw1   = (const float*)d_in[5];
  const float* rb1   = (const float*)d_in[6];
  const float* rw2   = (const float*)d_in[7];
  const float* rb2   = (const float*)d_in[8];
  const float* we1   = (const float*)d_in[9];
  const float* be1   = (const float*)d_in[10];
  const float* we2   = (const float*)d_in[11];
  const float* be2   = (const float*)d_in[12];
  const float* we3   = (const float*)d_in[13];
  const float* be3   = (const float*)d_in[14];
  const float* sw1   = (const float*)d_in[15];
  const float* sb1   = (const float*)d_in[16];
  const float* sw2   = (const float*)d_in[17];
  const float* sb2   = (const float*)d_in[18];
  const float* sres  = (const float*)d_in[19];
  float* out = (float*)d_out;

  char* ws = (char*)d_ws;
  size_t off = 0;
  auto alloc = [&](size_t bytes)->void*{ void* p = ws + off; off = (off + bytes + 255) & ~(size_t)255; return p; };
  float*          x     = (float*)alloc((size_t)NN*DIM*4);
  float*          y     = (float*)alloc((size_t)NN*DIM*4);
  float*          eo    = (float*)alloc((size_t)2*NASSIGN*DIM*4);
  unsigned short* tokb  = (unsigned short*)alloc((size_t)NN*DIM*2);
  uint8_t*        tokc  = (uint8_t*)alloc((size_t)NASSIGN*DIM);
  unsigned short* g1    = (unsigned short*)alloc((size_t)NN*DIM*2);
  uint8_t*        w1t   = (uint8_t*)alloc((size_t)NE*H2X*DIM);
  uint8_t*        w2t   = (uint8_t*)alloc((size_t)NE*H2X*INNER);
  uint8_t*        w3t   = (uint8_t*)alloc((size_t)NE*DIM*INNER);
  unsigned short* rw1t  = (unsigned short*)alloc((size_t)DIM*DIM*2);
  uint8_t*        h1    = (uint8_t*)alloc((size_t)NASSIGN*INNER);
  uint8_t*        h2b   = (uint8_t*)alloc((size_t)NASSIGN*INNER);
  int*            ridx  = (int*)alloc((size_t)NASSIGN*4);
  float*          rwt   = (float*)alloc((size_t)NASSIGN*4);
  int*            inv   = (int*)alloc((size_t)NASSIGN*4);
  int*            cnt   = (int*)alloc(128);
  int*            cnt2  = cnt + 8;
  float*          pooled= (float*)alloc((size_t)NB*DIM*4);

  tr_all_kernel<<<TR_N1+TR_N2+TR_N3+TR_N4, dim3(32,8), 0, stream>>>(
      we1, w1t, we2, w2t, we3, w3t, rw1, rw1t);
  convln_kernel<<<dim3(NT/CTT, NB), 384, 0, stream>>>(
      res, ln_g, ln_b, conv_w, conv_b, x, tokb, y);
  router_g1_kernel<<<dim3(DIM/128, NN/128), 256, 0, stream>>>(tokb, rw1t, rb1, g1, cnt);
  router2_kernel<<<NN/32, 256, 0, stream>>>(g1, rw2, rb2, ridx, rwt, cnt);
  fillcompact_kernel<<<NASSIGN/32, 256, 0, stream>>>(ridx, cnt, cnt2, inv, tokb, tokc, pooled);

  gemm_sg1_kernel<<<dim3(INNER/128, NN/64, NE), 256, 0, stream>>>(tokc, w1t, be1, cnt, h1);
  gemm_sg2_kernel<<<dim3(INNER/128, NN/64, NE), 256, 0, stream>>>(h1, w2t, be2, cnt, h2b);
  gemm_out_kernel<<<dim3(6, NN/64, NE), 256, 0, stream>>>(h2b, w3t, be3, cnt, eo);
  combine_pooled_kernel<<<dim3(NT/8, NB), 384, 0, stream>>>(
      eo, inv, rwt, x, sres, y, pooled);
  gatefinal_kernel<<<dim3(NT/8, NB), 384, 0, stream>>>(
      pooled, sw1, sb1, sw2, sb2, res, y, out);
}